// Round 7
// baseline (1087.866 us; speedup 1.0000x reference)
//
#include <hip/hip_runtime.h>
#include <hip/hip_bf16.h>

// GPT forward: B=2, T=1024, D=1024, H=16, HD=64, L=4, V=32000
// R7: (1) head k_gemm8: removed per-phase lgkmcnt(0)+sched_barrier(0) pinning
//     (m141: order-pinning costs ~40%; compiler auto-inserts fine-grained lgkm
//     waits for C++ ds_reads). (2) attention: 16 q-rows/wave -> 512 blocks
//     (2 blocks/CU, 2 waves/SIMD TLP).

typedef __attribute__((ext_vector_type(8))) short s16x8;
typedef __attribute__((ext_vector_type(4))) float fx4;

__device__ __forceinline__ unsigned short f2bf(float f) {
    union { float f; unsigned int u; } v; v.f = f;
    unsigned int r = v.u + 0x7FFFu + ((v.u >> 16) & 1u);
    return (unsigned short)(r >> 16);
}

__device__ __forceinline__ void gload16(const short* g, short* l) {
    __builtin_amdgcn_global_load_lds((const __attribute__((address_space(1))) void*)g,
                                     (__attribute__((address_space(3))) void*)l, 16, 0, 0);
}

__device__ __forceinline__ unsigned cvtpk(float a, float b) {
    unsigned r;
    asm("v_cvt_pk_bf16_f32 %0, %1, %2" : "=v"(r) : "v"(a), "v"(b));
    return r;
}

// ---------------- embedding ----------------
__global__ __launch_bounds__(256) void k_embed(const int* __restrict__ idx,
                                               const float* __restrict__ tok,
                                               const float* __restrict__ pos,
                                               float* __restrict__ x) {
    int r = blockIdx.x;
    int t = r & 1023;
    int tokid = idx[r];
    const float4* a = (const float4*)(tok + (size_t)tokid * 1024);
    const float4* p = (const float4*)(pos + (size_t)t * 1024);
    float4* o = (float4*)(x + (size_t)r * 1024);
    int i = threadIdx.x;
    float4 va = a[i], vp = p[i];
    va.x += vp.x; va.y += vp.y; va.z += vp.z; va.w += vp.w;
    o[i] = va;
}

// ---------------- layernorm (row of 1024), bf16 out ----------------
__global__ __launch_bounds__(256) void k_ln(const float* __restrict__ x,
                                            const float* __restrict__ w,
                                            const float* __restrict__ b,
                                            short* __restrict__ out) {
    int r = blockIdx.x;
    int tid = threadIdx.x;
    float4 v = ((const float4*)(x + (size_t)r * 1024))[tid];
    float s = v.x + v.y + v.z + v.w;
    float ss = v.x*v.x + v.y*v.y + v.z*v.z + v.w*v.w;
    __shared__ float red[8];
    #pragma unroll
    for (int off = 32; off; off >>= 1) { s += __shfl_down(s, off); ss += __shfl_down(ss, off); }
    int wid = tid >> 6;
    if ((tid & 63) == 0) { red[wid] = s; red[4 + wid] = ss; }
    __syncthreads();
    s = red[0] + red[1] + red[2] + red[3];
    ss = red[4] + red[5] + red[6] + red[7];
    float mean = s * (1.0f / 1024.0f);
    float var = ss * (1.0f / 1024.0f) - mean * mean;
    float rstd = rsqrtf(var + 1e-5f);
    float4 wv = ((const float4*)w)[tid];
    float4 bv = ((const float4*)b)[tid];
    union { unsigned short us[4]; unsigned long long ll; } pk;
    pk.us[0] = f2bf((v.x - mean) * rstd * wv.x + bv.x);
    pk.us[1] = f2bf((v.y - mean) * rstd * wv.y + bv.y);
    pk.us[2] = f2bf((v.z - mean) * rstd * wv.z + bv.z);
    pk.us[3] = f2bf((v.w - mean) * rstd * wv.w + bv.w);
    ((unsigned long long*)(out + (size_t)r * 1024))[tid] = pk.ll;
}

// ---------------- batched transpose+convert: all weights, one dispatch ----------------
__global__ __launch_bounds__(256) void k_tconv_all(
        const float* __restrict__ Wq, const float* __restrict__ Wk,
        const float* __restrict__ Wv, const float* __restrict__ Wo,
        const float* __restrict__ W1, const float* __restrict__ W2,
        const float* __restrict__ Wh,
        short* __restrict__ wqkv, short* __restrict__ wo,
        short* __restrict__ w1, short* __restrict__ w2, short* __restrict__ wh) {
    const int bid = blockIdx.x;
    const float* src; short* dst; int K, N, tile;
    if (bid < 4096) {
        int seg = bid >> 10;
        int r = bid & 1023;
        int l = r >> 8; tile = r & 255;
        K = 1024; N = 1024;
        if (seg == 0)      { src = Wq + (size_t)l * 1048576; dst = wqkv + (size_t)l * 3145728; }
        else if (seg == 1) { src = Wk + (size_t)l * 1048576; dst = wqkv + (size_t)l * 3145728 + 1048576; }
        else if (seg == 2) { src = Wv + (size_t)l * 1048576; dst = wqkv + (size_t)l * 3145728 + 2097152; }
        else               { src = Wo + (size_t)l * 1048576; dst = wo + (size_t)l * 1048576; }
    } else if (bid < 8192) {
        int r = bid - 4096; int l = r >> 10; tile = r & 1023;
        K = 1024; N = 4096; src = W1 + (size_t)l * 4194304; dst = w1 + (size_t)l * 4194304;
    } else if (bid < 12288) {
        int r = bid - 8192; int l = r >> 10; tile = r & 1023;
        K = 4096; N = 1024; src = W2 + (size_t)l * 4194304; dst = w2 + (size_t)l * 4194304;
    } else {
        tile = bid - 12288; K = 1024; N = 32000; src = Wh; dst = wh;
    }
    const int nTiles = N >> 6;
    const int kt = tile / nTiles, ntl = tile - kt * nTiles;
    const int n0 = ntl * 64, k0 = kt * 64;

    __shared__ float tl[64][65];
    const int tid = threadIdx.x;
    const int c4 = tid & 15, rr = tid >> 4;
    #pragma unroll
    for (int j = 0; j < 4; j++) {
        int row = rr + j * 16;
        float4 vv = *(const float4*)(src + (size_t)(k0 + row) * N + n0 + c4 * 4);
        tl[row][c4*4+0] = vv.x; tl[row][c4*4+1] = vv.y;
        tl[row][c4*4+2] = vv.z; tl[row][c4*4+3] = vv.w;
    }
    __syncthreads();
    const int c8 = tid & 7, r2 = tid >> 3;
    #pragma unroll
    for (int j = 0; j < 2; j++) {
        int nrow = r2 + j * 32;
        union { unsigned short us[8]; s16x8 v; } pk;
        #pragma unroll
        for (int e = 0; e < 8; e++) pk.us[e] = f2bf(tl[c8*8+e][nrow]);
        *(s16x8*)&dst[(size_t)(n0 + nrow) * K + k0 + c8 * 8] = pk.v;
    }
}

// ---------------- concat qkv bias: [L][3072] ----------------
__global__ __launch_bounds__(256) void k_bcat(const float* __restrict__ bq,
                                              const float* __restrict__ bk,
                                              const float* __restrict__ bv,
                                              float* __restrict__ o) {
    int i = blockIdx.x * 256 + threadIdx.x;
    int l = i / 3072, c = i % 3072;
    float v = (c < 1024) ? bq[l*1024 + c] : ((c < 2048) ? bk[l*1024 + c - 1024] : bv[l*1024 + c - 2048]);
    o[i] = v;
}

// ---------------- V transpose per (b,h) ----------------
__global__ __launch_bounds__(256) void k_vt(const short* __restrict__ qkv, short* __restrict__ vt) {
    int bh = blockIdx.y, b = bh >> 4, h = bh & 15;
    int t0 = blockIdx.x * 64;
    __shared__ short tile[64][72];
    int tid = threadIdx.x;
    int ch = tid & 7, rr = tid >> 3;
    const short* src = qkv + (size_t)b * 1024 * 3072 + 2048 + h * 64;
    #pragma unroll
    for (int j = 0; j < 2; j++) {
        int t = rr + j * 32;
        s16x8 v = *(const s16x8*)&src[(size_t)(t0 + t) * 3072 + ch * 8];
        *(s16x8*)&tile[t][ch * 8] = v;
    }
    __syncthreads();
    #pragma unroll
    for (int j = 0; j < 2; j++) {
        int hd = rr + j * 32;
        union { short ss[8]; s16x8 v; } pk;
        #pragma unroll
        for (int e = 0; e < 8; e++) pk.ss[e] = tile[ch * 8 + e][hd];
        *(s16x8*)&vt[(size_t)(bh * 64 + hd) * 1024 + t0 + ch * 8] = pk.v;
    }
}

// ---------------- 128-class GEMM (m97 structure), EPI + split-K support ----------------
// EPI: 0 = bias->bf16; 1 = f32 + residual; 2 = bias+GELU->bf16; 3 = f32 partial (no bias)
template<int MF, int EPI>
__global__ __launch_bounds__(256) void k_gemm(const short* __restrict__ A, const short* __restrict__ Bt,
                                              const float* bias, const float* res, void* Cout,
                                              int M, int N, int Kstride, int kLen,
                                              int mTiles, int nParts) {
    constexpr int BM = MF * 32;
    constexpr int IA = BM / 32;
    __shared__ __align__(16) short lA[BM * 64];
    __shared__ __align__(16) short lB[128 * 64];
    const int tid = threadIdx.x;
    const int l = tid & 63, w = tid >> 6;
    const int wr = w >> 1, wc = w & 1;
    const int per = gridDim.x >> 3;
    const int s2 = (blockIdx.x & 7) * per + (blockIdx.x >> 3);
    const int totPerN = mTiles * nParts;
    const int nt = s2 / totPerN;
    const int rem = s2 - nt * totPerN;
    const int part = rem / mTiles, mt = rem - part * mTiles;
    const int k0 = part * kLen;
    const int m0 = mt * BM, n0 = nt * 128;
    const int cl = l & 15, rh = l >> 4;
    fx4 acc[MF][4] = {};

    const int lr = l >> 3, c8 = l & 7;
    const short* pa[IA];
    const short* pb[4];
    #pragma unroll
    for (int j = 0; j < IA; j++) {
        const int row = w * (BM / 4) + j * 8 + lr;
        pa[j] = A + (size_t)(m0 + row) * Kstride + k0 + ((c8 ^ (row & 7)) << 3);
    }
    #pragma unroll
    for (int j = 0; j < 4; j++) {
        const int row = w * 32 + j * 8 + lr;
        pb[j] = Bt + (size_t)(n0 + row) * Kstride + k0 + ((c8 ^ (row & 7)) << 3);
    }

    for (int kt = 0; kt < kLen; kt += 64) {
        #pragma unroll
        for (int j = 0; j < IA; j++)
            gload16(pa[j] + kt, &lA[(w * (BM / 4) + j * 8) * 64]);
        #pragma unroll
        for (int j = 0; j < 4; j++)
            gload16(pb[j] + kt, &lB[(w * 32 + j * 8) * 64]);
        __syncthreads();
        #pragma unroll
        for (int kk = 0; kk < 2; kk++) {
            s16x8 af[MF], bfr[4];
            const int kc = kk * 4 + rh;
            const int ko = (kc ^ (cl & 7)) * 8;
            #pragma unroll
            for (int mf = 0; mf < MF; mf++)
                af[mf] = *(const s16x8*)&lA[(wr * (MF * 16) + mf * 16 + cl) * 64 + ko];
            #pragma unroll
            for (int nf = 0; nf < 4; nf++)
                bfr[nf] = *(const s16x8*)&lB[(wc * 64 + nf * 16 + cl) * 64 + ko];
            #pragma unroll
            for (int mf = 0; mf < MF; mf++)
                #pragma unroll
                for (int nf = 0; nf < 4; nf++)
                    acc[mf][nf] = __builtin_amdgcn_mfma_f32_16x16x32_bf16(af[mf], bfr[nf], acc[mf][nf], 0, 0, 0);
        }
        __syncthreads();
    }
    float* Cp = (float*)Cout + (size_t)part * M * N;
    #pragma unroll
    for (int nf = 0; nf < 4; nf++) {
        const int col = n0 + wc * 64 + nf * 16 + cl;
        const float bv = (EPI == 3) ? 0.0f : bias[col];
        #pragma unroll
        for (int mf = 0; mf < MF; mf++) {
            const int rbase = m0 + wr * (MF * 16) + mf * 16 + rh * 4;
            #pragma unroll
            for (int r = 0; r < 4; r++) {
                float v = acc[mf][nf][r] + bv;
                const size_t off = (size_t)(rbase + r) * N + col;
                if constexpr (EPI == 0) {
                    ((unsigned short*)Cout)[off] = f2bf(v);
                } else if constexpr (EPI == 1) {
                    ((float*)Cout)[off] = v + res[off];
                } else if constexpr (EPI == 2) {
                    v = 0.5f * v * (1.0f + erff(v * 0.70710678118654752f));
                    ((unsigned short*)Cout)[off] = f2bf(v);
                } else {
                    Cp[off] = v;
                }
            }
        }
    }
}

// ---------------- split-K reduce: x += p0+p1+p2+p3 + bias ----------------
__global__ __launch_bounds__(256) void k_red4(const float* __restrict__ part,
                                              const float* __restrict__ bias,
                                              float* __restrict__ x) {
    const size_t PS = (size_t)2048 * 1024;
    const int r = blockIdx.x, i = threadIdx.x;
    const size_t base = (size_t)r * 1024 + i * 4;
    float4 a = *(const float4*)(part + base);
    float4 b = *(const float4*)(part + PS + base);
    float4 c = *(const float4*)(part + 2 * PS + base);
    float4 d = *(const float4*)(part + 3 * PS + base);
    float4 xv = *(const float4*)(x + base);
    float4 bb = *(const float4*)(bias + i * 4);
    xv.x += a.x + b.x + c.x + d.x + bb.x;
    xv.y += a.y + b.y + c.y + d.y + bb.y;
    xv.z += a.z + b.z + c.z + d.z + bb.z;
    xv.w += a.w + b.w + c.w + d.w + bb.w;
    *(float4*)(x + base) = xv;
}

// ---------------- 8-phase 256x256 GEMM (head), f32 out, no bias ----------------
// No per-phase lgkmcnt(0)/sched_barrier pinning: compiler inserts fine-grained
// lgkm waits for the C++ ds_reads (m97 evidence); m141 showed full pinning -40%.
#define PH_CORE(MB) \
    __builtin_amdgcn_s_barrier(); \
    __builtin_amdgcn_s_setprio(1); \
    _Pragma("unroll") \
    for (int nf_ = 0; nf_ < 4; ++nf_) { \
        acc[MB][nf_]   = __builtin_amdgcn_mfma_f32_16x16x32_bf16(af[0][0], bf[nf_][0], acc[MB][nf_], 0, 0, 0); \
        acc[MB][nf_]   = __builtin_amdgcn_mfma_f32_16x16x32_bf16(af[0][1], bf[nf_][1], acc[MB][nf_], 0, 0, 0); \
        acc[MB+1][nf_] = __builtin_amdgcn_mfma_f32_16x16x32_bf16(af[1][0], bf[nf_][0], acc[MB+1][nf_], 0, 0, 0); \
        acc[MB+1][nf_] = __builtin_amdgcn_mfma_f32_16x16x32_bf16(af[1][1], bf[nf_][1], acc[MB+1][nf_], 0, 0, 0); \
    } \
    __builtin_amdgcn_s_setprio(0);

#define PHN(MB) \
    PH_CORE(MB) \
    asm volatile("" ::: "memory"); \
    __builtin_amdgcn_s_barrier(); \
    asm volatile("" ::: "memory");

#define PHW(MB) \
    PH_CORE(MB) \
    asm volatile("s_waitcnt vmcnt(4)" ::: "memory"); \
    __builtin_amdgcn_s_barrier(); \
    asm volatile("" ::: "memory");

__global__ __launch_bounds__(512, 1)
void k_gemm8(const short* __restrict__ A, const short* __restrict__ Bt,
             float* __restrict__ C, int M, int N, int K, int mTiles) {
    __shared__ __align__(16) short lA[2][256 * 64];
    __shared__ __align__(16) short lB[2][256 * 64];
    const int tid = threadIdx.x;
    const int l = tid & 63, w = tid >> 6;
    const int wr = w >> 2, wc = w & 3;
    const int per = gridDim.x >> 3;
    const int s2 = (blockIdx.x & 7) * per + (blockIdx.x >> 3);
    const int nt0 = s2 / mTiles, mt = s2 - nt0 * mTiles;
    const int m0 = mt * 256, n0 = nt0 * 256;
    const int cl = l & 15, rh = l >> 4;

    fx4 acc[8][4] = {};

    const int srow = tid >> 3, sc8 = tid & 7;
    const short* pA[2][2]; const short* pB[2][2];
    #pragma unroll
    for (int hh = 0; hh < 2; ++hh)
        #pragma unroll
        for (int j = 0; j < 2; ++j) {
            const int row = hh * 128 + j * 64 + srow;
            const int cg = (sc8 ^ (row & 7)) << 3;
            pA[hh][j] = A + (size_t)(m0 + row) * K + cg;
            pB[hh][j] = Bt + (size_t)(n0 + row) * K + cg;
        }

    auto stageA = [&](int b, int hh, int kt) {
        #pragma unroll
        for (int j = 0; j < 2; ++j)
            gload16(pA[hh][j] + (kt << 6), &lA[b][(hh * 128 + j * 64 + w * 8) * 64]);
    };
    auto stageB = [&](int b, int hh, int kt) {
        #pragma unroll
        for (int j = 0; j < 2; ++j)
            gload16(pB[hh][j] + (kt << 6), &lB[b][(hh * 128 + j * 64 + w * 8) * 64]);
    };
    auto readA = [&](int b, int mf, int kk) -> s16x8 {
        const int row = wr * 128 + mf * 16 + cl;
        return *(const s16x8*)&lA[b][(row << 6) + (((kk * 4 + rh) ^ (row & 7)) << 3)];
    };
    auto readB = [&](int b, int nf, int kk) -> s16x8 {
        const int row = wc * 64 + nf * 16 + cl;
        return *(const s16x8*)&lB[b][(row << 6) + (((kk * 4 + rh) ^ (row & 7)) << 3)];
    };

    const int NT = K >> 6;
    stageA(0, 0, 0); stageA(0, 1, 0);
    stageB(0, 0, 0); stageB(0, 1, 0);
    stageB(1, 0, 1); stageB(1, 1, 1);
    asm volatile("s_waitcnt vmcnt(4)" ::: "memory");
    __builtin_amdgcn_s_barrier();
    asm volatile("" ::: "memory");

    s16x8 bf[4][2], af[2][2];
    for (int c = 0; c < (NT >> 1); ++c) {
        const int kt = c << 1;
        const int k1 = kt + 1;
        const int k2 = (kt + 2 < NT) ? kt + 2 : NT - 1;
        const int k3 = (kt + 3 < NT) ? kt + 3 : NT - 1;

        #pragma unroll
        for (int nf = 0; nf < 4; ++nf) { bf[nf][0] = readB(0, nf, 0); bf[nf][1] = readB(0, nf, 1); }
        af[0][0] = readA(0, 0, 0); af[0][1] = readA(0, 0, 1);
        af[1][0] = readA(0, 1, 0); af[1][1] = readA(0, 1, 1);
        stageA(1, 0, k1); stageA(1, 1, k1);
        PHN(0)
        af[0][0] = readA(0, 2, 0); af[0][1] = readA(0, 2, 1);
        af[1][0] = readA(0, 3, 0); af[1][1] = readA(0, 3, 1);
        stageB(0, 0, k2);
        PHN(2)
        af[0][0] = readA(0, 4, 0); af[0][1] = readA(0, 4, 1);
        af[1][0] = readA(0, 5, 0); af[1][1] = readA(0, 5, 1);
        stageB(0, 1, k2);
        PHN(4)
        af[0][0] = readA(0, 6, 0); af[0][1] = readA(0, 6, 1);
        af[1][0] = readA(0, 7, 0); af[1][1] = readA(0, 7, 1);
        PHW(6)
        #pragma unroll
        for (int nf = 0; nf < 4; ++nf) { bf[nf][0] = readB(1, nf, 0); bf[nf][1] = readB(1, nf, 1); }
        af[0][0] = readA(1, 0, 0); af[0][1] = readA(1, 0, 1);
        af[1][0] = readA(1, 1, 0); af[1][1] = readA(1, 1, 1);
        stageA(0, 0, k2);
        PHN(0)
        af[0][0] = readA(1, 2, 0); af[0][1] = readA(1, 2, 1);
        af[1][0] = readA(1, 3, 0); af[1][1] = readA(1, 3, 1);
        stageA(0, 1, k2);
        PHN(2)
        af[0][0] = readA(1, 4, 0); af[0][1] = readA(1, 4, 1);
        af[1][0] = readA(1, 5, 0); af[1][1] = readA(1, 5, 1);
        stageB(1, 0, k3);
        PHN(4)
        af[0][0] = readA(1, 6, 0); af[0][1] = readA(1, 6, 1);
        af[1][0] = readA(1, 7, 0); af[1][1] = readA(1, 7, 1);
        stageB(1, 1, k3);
        PHW(6)
    }

    #pragma unroll
    for (int mf = 0; mf < 8; ++mf) {
        const int rbase = m0 + wr * 128 + mf * 16 + rh * 4;
        #pragma unroll
        for (int nf = 0; nf < 4; ++nf) {
            const int col = n0 + wc * 64 + nf * 16 + cl;
            #pragma unroll
            for (int r = 0; r < 4; ++r)
                C[(size_t)(rbase + r) * N + col] = acc[mf][nf][r];
        }
    }
}

// ---------------- fused causal attention, 16 q-rows/wave (2 blocks/CU) ----------------
// S^T = K·Q^T; softmax over k in-lane + shfl_xor(16,32); P packed bf16 via
// XOR-swizzled per-wave LDS; O^T = V^T·P^T; vectorized stores.
__global__ __launch_bounds__(256) void k_attn(const short* __restrict__ qkv,
                                              const short* __restrict__ vt,
                                              short* __restrict__ y) {
    const int bh = blockIdx.y, qt = blockIdx.x;
    const int b = bh >> 4, h = bh & 15;
    const int w = threadIdx.x >> 6, l = threadIdx.x & 63;
    const int cl = l & 15, rh = l >> 4;
    const int q0 = qt * 64 + w * 16;
    const short* qbase = qkv + (size_t)b * 1024 * 3072 + h * 64;
    const short* kbase = qbase + 1024;
    const short* vbase = vt + (size_t)bh * 64 * 1024;
    __shared__ __align__(16) short plds[4][16][64];
    char* pbase = (char*)&plds[w][0][0];

    s16x8 qf[2];
    #pragma unroll
    for (int kf = 0; kf < 2; kf++)
        qf[kf] = *(const s16x8*)&qbase[(size_t)(q0 + cl) * 3072 + kf * 32 + rh * 8];

    fx4 oacc[4] = {};
    float mrow = -3e38f, lrow = 0.0f;
    const float SC = 0.125f * 1.44269504088896f;   // scale * log2(e)

    const int ntile = (q0 + 79) >> 6;
    for (int it = 0; it < ntile; it++) {
        const int t0 = it * 64;
        fx4 s[4] = {};
        #pragma unroll
        for (int kf = 0; kf < 2; kf++) {
            s16x8 kfr[4];
            #pragma unroll
            for (int m = 0; m < 4; m++)
                kfr[m] = *(const s16x8*)&kbase[(size_t)(t0 + m * 16 + cl) * 3072 + kf * 32 + rh * 8];
            #pragma unroll
            for (int m = 0; m < 4; m++)
                s[m] = __builtin_amdgcn_mfma_f32_16x16x32_bf16(kfr[m], qf[kf], s[m], 0, 0, 0);
        }
        const bool domask = (t0 + 63) > q0;
        {
            const int q = q0 + cl;
            float tmax = -3e38f;
            #pragma unroll
            for (int m = 0; m < 4; m++)
                #pragma unroll
                for (int r = 0; r < 4; r++) {
                    float v = s[m][r] * SC;
                    if (domask && (t0 + m * 16 + rh * 4 + r) > q) v = -3e38f;
                    s[m][r] = v;
                    tmax = fmaxf(tmax, v);
                }
            tmax = fmaxf(tmax, __shfl_xor(tmax, 16));
            tmax = fmaxf(tmax, __shfl_xor(tmax, 32));
            const float mnew = fmaxf(mrow, tmax);
            const float alpha = exp2f(mrow - mnew);
            mrow = mnew;
            float rsum = 0.0f;
            #pragma unroll
            for (int m = 0; m < 4; m++)
                #pragma unroll
                for (int r = 0; r < 4; r++) {
                    float p = exp2f(s[m][r] - mnew);
                    s[m][r] = p;
                    rsum += p;
                }
            rsum += __shfl_xor(rsum, 16);
            rsum += __shfl_xor(rsum, 32);
            lrow = lrow * alpha + rsum;
            #pragma unroll
            for (int mp = 0; mp < 4; mp++)
                #pragma unroll
                for (int r = 0; r < 4; r++)
                    oacc[mp][r] *= alpha;
        }
        // pack P -> per-wave LDS [q][k], b64 writes, XOR swizzle
        {
            const int qr = cl;
            const int sw = (qr & 7) << 4;
            #pragma unroll
            for (int m = 0; m < 4; m++) {
                uint2 pk2;
                pk2.x = cvtpk(s[m][0], s[m][1]);
                pk2.y = cvtpk(s[m][2], s[m][3]);
                const int off = qr * 128 + ((m * 32 + rh * 8) ^ sw);
                *(uint2*)(pbase + off) = pk2;
            }
        }
        s16x8 pb2[2];
        {
            const int qr = cl;
            const int sw = (qr & 7) << 4;
            #pragma unroll
            for (int kf = 0; kf < 2; kf++)
                pb2[kf] = *(const s16x8*)(pbase + qr * 128 + ((kf * 64 + rh * 16) ^ sw));
        }
        s16x8 vf[4][2];
        #pragma unroll
        for (int mp = 0; mp < 4; mp++)
            #pragma unroll
            for (int kf = 0; kf < 2; kf++)
                vf[mp][kf] = *(const s16x8*)&vbase[(size_t)(mp * 16 + cl) * 1024 + t0 + kf * 32 + rh * 8];
        #pragma unroll
        for (int mp = 0; mp < 4; mp++)
            #pragma unroll
            for (int kf = 0; kf < 2; kf++)
                oacc[mp] = __builtin_amdgcn_mfma_f32_16x16x32_bf16(vf[mp][kf], pb2[kf], oacc[mp], 0, 0, 0);
    }
    {
        const float inv = 1.0f / lrow;
        const int q = q0 + cl;
        #pragma unroll
        for (int mp = 0; mp < 4; mp++) {
            uint2 pk2;
            pk2.x = cvtpk(oacc[mp][0] * inv, oacc[mp][1] * inv);
            pk2.y = cvtpk(oacc[mp][2] * inv, oacc[mp][3] * inv);
            *(uint2*)&y[(size_t)(b * 1024 + q) * 1024 + h * 64 + mp * 16 + rh * 4] = pk2;
        }
    }
}

// ---------------- host launcher ----------------
extern "C" void kernel_launch(void* const* d_in, const int* in_sizes, int n_in,
                              void* d_out, int out_size, void* d_ws, size_t ws_size,
                              hipStream_t stream) {
    const int*   idx   = (const int*)d_in[0];
    const float* tok   = (const float*)d_in[1];
    const float* pos   = (const float*)d_in[2];
    const float* ln1w  = (const float*)d_in[3];
    const float* ln1b  = (const float*)d_in[4];
    const float* Wq    = (const float*)d_in[5];
    const float* bq    = (const float*)d_in[6];
    const float* Wk    = (const float*)d_in[7];
    const float* bk    = (const float*)d_in[8];
    const float* Wv    = (const float*)d_in[9];
    const float* bv    = (const float*)d_in[10];
    const float* Wo    = (const float*)d_in[11];
    const float* bo    = (const float*)d_in[12];
    const float* ln2w  = (const float*)d_in[13];
    const float* ln2b  = (const float*)d_in[14];
    const float* W1    = (const float*)d_in[15];
    const float* b1    = (const float*)d_in[16];
    const float* W2    = (const float*)d_in[17];
    const float* b2    = (const float*)d_in[18];
    const float* lnfw  = (const float*)d_in[19];
    const float* lnfb  = (const float*)d_in[20];
    const float* headw = (const float*)d_in[21];

    char* ws = (char*)d_ws;
    size_t off = 0;
    auto nalloc = [&](size_t bytes) -> char* {
        char* p = ws + off;
        off = (off + bytes + 255) & ~(size_t)255;
        return p;
    };
    float* x     = (float*)nalloc((size_t)2048 * 1024 * 4);
    short* h     = (short*)nalloc((size_t)2048 * 1024 * 2);
    short* qkv   = (short*)nalloc((size_t)2048 * 3072 * 2);
    short* vtb   = (short*)nalloc((size_t)32 * 64 * 1024 * 2);
    short* y     = (short*)nalloc((size_t)2048 * 1024 * 2);
    short* u     = (short*)nalloc((size_t)2048 * 4096 * 2);
    float* mpart = (float*)nalloc((size_t)4 * 2048 * 1024 * 4);
    short* wqkv  = (short*)nalloc((size_t)4 * 3072 * 1024 * 2);
    short* wo    = (short*)nalloc((size_t)4 * 1024 * 1024 * 2);
    short* w1    = (short*)nalloc((size_t)4 * 4096 * 1024 * 2);
    short* w2    = (short*)nalloc((size_t)4 * 1024 * 4096 * 2);
    short* wh    = (short*)nalloc((size_t)32000 * 1024 * 2);
    float* bqkv  = (float*)nalloc((size_t)4 * 3072 * 4);

    // ---- weight prep ----
    k_bcat<<<48, 256, 0, stream>>>(bq, bk, bv, bqkv);
    k_tconv_all<<<20288, 256, 0, stream>>>(Wq, Wk, Wv, Wo, W1, W2, headw,
                                           wqkv, wo, w1, w2, wh);

    // ---- forward ----
    k_embed<<<2048, 256, 0, stream>>>(idx, tok, pos, x);
    for (int lyr = 0; lyr < 4; lyr++) {
        k_ln<<<2048, 256, 0, stream>>>(x, ln1w + lyr * 1024, ln1b + lyr * 1024, h);
        k_gemm<2, 0><<<768, 256, 0, stream>>>(h, wqkv + (size_t)lyr * 3072 * 1024, bqkv + lyr * 3072,
                                              nullptr, qkv, 2048, 3072, 1024, 1024, 32, 1);
        k_vt<<<dim3(16, 32), 256, 0, stream>>>(qkv, vtb);
        k_attn<<<dim3(16, 32), 256, 0, stream>>>(qkv, vtb, y);
        k_gemm<2, 1><<<256, 256, 0, stream>>>(y, wo + (size_t)lyr * 1024 * 1024, bo + lyr * 1024,
                                              x, x, 2048, 1024, 1024, 1024, 32, 1);
        k_ln<<<2048, 256, 0, stream>>>(x, ln2w + lyr * 1024, ln2b + lyr * 1024, h);
        k_gemm<2, 2><<<1024, 256, 0, stream>>>(h, w1 + (size_t)lyr * 4194304, b1 + lyr * 4096,
                                               nullptr, u, 2048, 4096, 1024, 1024, 32, 1);
        k_gemm<2, 3><<<1024, 256, 0, stream>>>(u, w2 + (size_t)lyr * 4194304, nullptr,
                                               nullptr, mpart, 2048, 1024, 4096, 1024, 32, 4);
        k_red4<<<2048, 256, 0, stream>>>(mpart, b2 + lyr * 1024, x);
    }
    k_ln<<<2048, 256, 0, stream>>>(x, lnfw, lnfb, h);
    k_gemm8<<<1000, 512, 0, stream>>>(h, wh, (float*)d_out, 2048, 32000, 1024, 8);
    (void)in_sizes; (void)n_in; (void)out_size; (void)ws_size;
}

// Round 8
// 1010.516 us; speedup vs baseline: 1.0765x; 1.0765x over previous
//
#include <hip/hip_runtime.h>
#include <hip/hip_bf16.h>

// GPT forward: B=2, T=1024, D=1024, H=16, HD=64, L=4, V=32000
// R8: attention: back to 32 q-rows/wave + block-shared K/V LDS staging
//     (dbuf, counted vmcnt(4), raw barriers) — K/V L2 traffic /4, latency hidden.
//     Fusions: k_embedln (embed+LN), k_redln (splitK-reduce+bias+residual+LN).

typedef __attribute__((ext_vector_type(8))) short s16x8;
typedef __attribute__((ext_vector_type(4))) float fx4;

__device__ __forceinline__ unsigned short f2bf(float f) {
    union { float f; unsigned int u; } v; v.f = f;
    unsigned int r = v.u + 0x7FFFu + ((v.u >> 16) & 1u);
    return (unsigned short)(r >> 16);
}

__device__ __forceinline__ void gload16(const short* g, short* l) {
    __builtin_amdgcn_global_load_lds((const __attribute__((address_space(1))) void*)g,
                                     (__attribute__((address_space(3))) void*)l, 16, 0, 0);
}

__device__ __forceinline__ unsigned cvtpk(float a, float b) {
    unsigned r;
    asm("v_cvt_pk_bf16_f32 %0, %1, %2" : "=v"(r) : "v"(a), "v"(b));
    return r;
}

// ---------------- embed + LN fused (row-local) ----------------
__global__ __launch_bounds__(256) void k_embedln(const int* __restrict__ idx,
                                                 const float* __restrict__ tok,
                                                 const float* __restrict__ pos,
                                                 const float* __restrict__ lw,
                                                 const float* __restrict__ lb,
                                                 float* __restrict__ x,
                                                 short* __restrict__ out) {
    int r = blockIdx.x;
    int t = r & 1023;
    int tokid = idx[r];
    int tid = threadIdx.x;
    float4 v = ((const float4*)(tok + (size_t)tokid * 1024))[tid];
    float4 vp = ((const float4*)(pos + (size_t)t * 1024))[tid];
    v.x += vp.x; v.y += vp.y; v.z += vp.z; v.w += vp.w;
    ((float4*)(x + (size_t)r * 1024))[tid] = v;
    float s = v.x + v.y + v.z + v.w;
    float ss = v.x*v.x + v.y*v.y + v.z*v.z + v.w*v.w;
    __shared__ float red[8];
    #pragma unroll
    for (int off = 32; off; off >>= 1) { s += __shfl_down(s, off); ss += __shfl_down(ss, off); }
    int wid = tid >> 6;
    if ((tid & 63) == 0) { red[wid] = s; red[4 + wid] = ss; }
    __syncthreads();
    s = red[0] + red[1] + red[2] + red[3];
    ss = red[4] + red[5] + red[6] + red[7];
    float mean = s * (1.0f / 1024.0f);
    float var = ss * (1.0f / 1024.0f) - mean * mean;
    float rstd = rsqrtf(var + 1e-5f);
    float4 wv = ((const float4*)lw)[tid];
    float4 bv = ((const float4*)lb)[tid];
    union { unsigned short us[4]; unsigned long long ll; } pk;
    pk.us[0] = f2bf((v.x - mean) * rstd * wv.x + bv.x);
    pk.us[1] = f2bf((v.y - mean) * rstd * wv.y + bv.y);
    pk.us[2] = f2bf((v.z - mean) * rstd * wv.z + bv.z);
    pk.us[3] = f2bf((v.w - mean) * rstd * wv.w + bv.w);
    ((unsigned long long*)(out + (size_t)r * 1024))[tid] = pk.ll;
}

// ---------------- layernorm (row of 1024), bf16 out ----------------
__global__ __launch_bounds__(256) void k_ln(const float* __restrict__ x,
                                            const float* __restrict__ w,
                                            const float* __restrict__ b,
                                            short* __restrict__ out) {
    int r = blockIdx.x;
    int tid = threadIdx.x;
    float4 v = ((const float4*)(x + (size_t)r * 1024))[tid];
    float s = v.x + v.y + v.z + v.w;
    float ss = v.x*v.x + v.y*v.y + v.z*v.z + v.w*v.w;
    __shared__ float red[8];
    #pragma unroll
    for (int off = 32; off; off >>= 1) { s += __shfl_down(s, off); ss += __shfl_down(ss, off); }
    int wid = tid >> 6;
    if ((tid & 63) == 0) { red[wid] = s; red[4 + wid] = ss; }
    __syncthreads();
    s = red[0] + red[1] + red[2] + red[3];
    ss = red[4] + red[5] + red[6] + red[7];
    float mean = s * (1.0f / 1024.0f);
    float var = ss * (1.0f / 1024.0f) - mean * mean;
    float rstd = rsqrtf(var + 1e-5f);
    float4 wv = ((const float4*)w)[tid];
    float4 bv = ((const float4*)b)[tid];
    union { unsigned short us[4]; unsigned long long ll; } pk;
    pk.us[0] = f2bf((v.x - mean) * rstd * wv.x + bv.x);
    pk.us[1] = f2bf((v.y - mean) * rstd * wv.y + bv.y);
    pk.us[2] = f2bf((v.z - mean) * rstd * wv.z + bv.z);
    pk.us[3] = f2bf((v.w - mean) * rstd * wv.w + bv.w);
    ((unsigned long long*)(out + (size_t)r * 1024))[tid] = pk.ll;
}

// ---------------- splitK reduce + bias + residual + LN fused ----------------
__global__ __launch_bounds__(256) void k_redln(const float* __restrict__ part,
                                               const float* __restrict__ bias,
                                               float* __restrict__ x,
                                               const float* __restrict__ lw,
                                               const float* __restrict__ lb,
                                               short* __restrict__ out) {
    const size_t PS = (size_t)2048 * 1024;
    const int r = blockIdx.x;
    const int tid = threadIdx.x;
    const size_t base = (size_t)r * 1024 + tid * 4;
    float4 a = *(const float4*)(part + base);
    float4 b = *(const float4*)(part + PS + base);
    float4 c = *(const float4*)(part + 2 * PS + base);
    float4 d = *(const float4*)(part + 3 * PS + base);
    float4 v = *(const float4*)(x + base);
    float4 bb = *(const float4*)(bias + tid * 4);
    v.x += a.x + b.x + c.x + d.x + bb.x;
    v.y += a.y + b.y + c.y + d.y + bb.y;
    v.z += a.z + b.z + c.z + d.z + bb.z;
    v.w += a.w + b.w + c.w + d.w + bb.w;
    *(float4*)(x + base) = v;
    float s = v.x + v.y + v.z + v.w;
    float ss = v.x*v.x + v.y*v.y + v.z*v.z + v.w*v.w;
    __shared__ float red[8];
    #pragma unroll
    for (int off = 32; off; off >>= 1) { s += __shfl_down(s, off); ss += __shfl_down(ss, off); }
    int wid = tid >> 6;
    if ((tid & 63) == 0) { red[wid] = s; red[4 + wid] = ss; }
    __syncthreads();
    s = red[0] + red[1] + red[2] + red[3];
    ss = red[4] + red[5] + red[6] + red[7];
    float mean = s * (1.0f / 1024.0f);
    float var = ss * (1.0f / 1024.0f) - mean * mean;
    float rstd = rsqrtf(var + 1e-5f);
    float4 wv = ((const float4*)lw)[tid];
    float4 bv = ((const float4*)lb)[tid];
    union { unsigned short us[4]; unsigned long long ll; } pk;
    pk.us[0] = f2bf((v.x - mean) * rstd * wv.x + bv.x);
    pk.us[1] = f2bf((v.y - mean) * rstd * wv.y + bv.y);
    pk.us[2] = f2bf((v.z - mean) * rstd * wv.z + bv.z);
    pk.us[3] = f2bf((v.w - mean) * rstd * wv.w + bv.w);
    ((unsigned long long*)(out + (size_t)r * 1024))[tid] = pk.ll;
}

// ---------------- batched transpose+convert: all weights, one dispatch ----------------
__global__ __launch_bounds__(256) void k_tconv_all(
        const float* __restrict__ Wq, const float* __restrict__ Wk,
        const float* __restrict__ Wv, const float* __restrict__ Wo,
        const float* __restrict__ W1, const float* __restrict__ W2,
        const float* __restrict__ Wh,
        short* __restrict__ wqkv, short* __restrict__ wo,
        short* __restrict__ w1, short* __restrict__ w2, short* __restrict__ wh) {
    const int bid = blockIdx.x;
    const float* src; short* dst; int K, N, tile;
    if (bid < 4096) {
        int seg = bid >> 10;
        int r = bid & 1023;
        int l = r >> 8; tile = r & 255;
        K = 1024; N = 1024;
        if (seg == 0)      { src = Wq + (size_t)l * 1048576; dst = wqkv + (size_t)l * 3145728; }
        else if (seg == 1) { src = Wk + (size_t)l * 1048576; dst = wqkv + (size_t)l * 3145728 + 1048576; }
        else if (seg == 2) { src = Wv + (size_t)l * 1048576; dst = wqkv + (size_t)l * 3145728 + 2097152; }
        else               { src = Wo + (size_t)l * 1048576; dst = wo + (size_t)l * 1048576; }
    } else if (bid < 8192) {
        int r = bid - 4096; int l = r >> 10; tile = r & 1023;
        K = 1024; N = 4096; src = W1 + (size_t)l * 4194304; dst = w1 + (size_t)l * 4194304;
    } else if (bid < 12288) {
        int r = bid - 8192; int l = r >> 10; tile = r & 1023;
        K = 4096; N = 1024; src = W2 + (size_t)l * 4194304; dst = w2 + (size_t)l * 4194304;
    } else {
        tile = bid - 12288; K = 1024; N = 32000; src = Wh; dst = wh;
    }
    const int nTiles = N >> 6;
    const int kt = tile / nTiles, ntl = tile - kt * nTiles;
    const int n0 = ntl * 64, k0 = kt * 64;

    __shared__ float tl[64][65];
    const int tid = threadIdx.x;
    const int c4 = tid & 15, rr = tid >> 4;
    #pragma unroll
    for (int j = 0; j < 4; j++) {
        int row = rr + j * 16;
        float4 vv = *(const float4*)(src + (size_t)(k0 + row) * N + n0 + c4 * 4);
        tl[row][c4*4+0] = vv.x; tl[row][c4*4+1] = vv.y;
        tl[row][c4*4+2] = vv.z; tl[row][c4*4+3] = vv.w;
    }
    __syncthreads();
    const int c8 = tid & 7, r2 = tid >> 3;
    #pragma unroll
    for (int j = 0; j < 2; j++) {
        int nrow = r2 + j * 32;
        union { unsigned short us[8]; s16x8 v; } pk;
        #pragma unroll
        for (int e = 0; e < 8; e++) pk.us[e] = f2bf(tl[c8*8+e][nrow]);
        *(s16x8*)&dst[(size_t)(n0 + nrow) * K + k0 + c8 * 8] = pk.v;
    }
}

// ---------------- concat qkv bias: [L][3072] ----------------
__global__ __launch_bounds__(256) void k_bcat(const float* __restrict__ bq,
                                              const float* __restrict__ bk,
                                              const float* __restrict__ bv,
                                              float* __restrict__ o) {
    int i = blockIdx.x * 256 + threadIdx.x;
    int l = i / 3072, c = i % 3072;
    float v = (c < 1024) ? bq[l*1024 + c] : ((c < 2048) ? bk[l*1024 + c - 1024] : bv[l*1024 + c - 2048]);
    o[i] = v;
}

// ---------------- V transpose per (b,h) ----------------
__global__ __launch_bounds__(256) void k_vt(const short* __restrict__ qkv, short* __restrict__ vt) {
    int bh = blockIdx.y, b = bh >> 4, h = bh & 15;
    int t0 = blockIdx.x * 64;
    __shared__ short tile[64][72];
    int tid = threadIdx.x;
    int ch = tid & 7, rr = tid >> 3;
    const short* src = qkv + (size_t)b * 1024 * 3072 + 2048 + h * 64;
    #pragma unroll
    for (int j = 0; j < 2; j++) {
        int t = rr + j * 32;
        s16x8 v = *(const s16x8*)&src[(size_t)(t0 + t) * 3072 + ch * 8];
        *(s16x8*)&tile[t][ch * 8] = v;
    }
    __syncthreads();
    #pragma unroll
    for (int j = 0; j < 2; j++) {
        int hd = rr + j * 32;
        union { short ss[8]; s16x8 v; } pk;
        #pragma unroll
        for (int e = 0; e < 8; e++) pk.ss[e] = tile[ch * 8 + e][hd];
        *(s16x8*)&vt[(size_t)(bh * 64 + hd) * 1024 + t0 + ch * 8] = pk.v;
    }
}

// ---------------- 128-class GEMM (m97 structure), EPI + split-K support ----------------
// EPI: 0 = bias->bf16; 1 = f32 + residual; 2 = bias+GELU->bf16; 3 = f32 partial (no bias)
template<int MF, int EPI>
__global__ __launch_bounds__(256) void k_gemm(const short* __restrict__ A, const short* __restrict__ Bt,
                                              const float* bias, const float* res, void* Cout,
                                              int M, int N, int Kstride, int kLen,
                                              int mTiles, int nParts) {
    constexpr int BM = MF * 32;
    constexpr int IA = BM / 32;
    __shared__ __align__(16) short lA[BM * 64];
    __shared__ __align__(16) short lB[128 * 64];
    const int tid = threadIdx.x;
    const int l = tid & 63, w = tid >> 6;
    const int wr = w >> 1, wc = w & 1;
    const int per = gridDim.x >> 3;
    const int s2 = (blockIdx.x & 7) * per + (blockIdx.x >> 3);
    const int totPerN = mTiles * nParts;
    const int nt = s2 / totPerN;
    const int rem = s2 - nt * totPerN;
    const int part = rem / mTiles, mt = rem - part * mTiles;
    const int k0 = part * kLen;
    const int m0 = mt * BM, n0 = nt * 128;
    const int cl = l & 15, rh = l >> 4;
    fx4 acc[MF][4] = {};

    const int lr = l >> 3, c8 = l & 7;
    const short* pa[IA];
    const short* pb[4];
    #pragma unroll
    for (int j = 0; j < IA; j++) {
        const int row = w * (BM / 4) + j * 8 + lr;
        pa[j] = A + (size_t)(m0 + row) * Kstride + k0 + ((c8 ^ (row & 7)) << 3);
    }
    #pragma unroll
    for (int j = 0; j < 4; j++) {
        const int row = w * 32 + j * 8 + lr;
        pb[j] = Bt + (size_t)(n0 + row) * Kstride + k0 + ((c8 ^ (row & 7)) << 3);
    }

    for (int kt = 0; kt < kLen; kt += 64) {
        #pragma unroll
        for (int j = 0; j < IA; j++)
            gload16(pa[j] + kt, &lA[(w * (BM / 4) + j * 8) * 64]);
        #pragma unroll
        for (int j = 0; j < 4; j++)
            gload16(pb[j] + kt, &lB[(w * 32 + j * 8) * 64]);
        __syncthreads();
        #pragma unroll
        for (int kk = 0; kk < 2; kk++) {
            s16x8 af[MF], bfr[4];
            const int kc = kk * 4 + rh;
            const int ko = (kc ^ (cl & 7)) * 8;
            #pragma unroll
            for (int mf = 0; mf < MF; mf++)
                af[mf] = *(const s16x8*)&lA[(wr * (MF * 16) + mf * 16 + cl) * 64 + ko];
            #pragma unroll
            for (int nf = 0; nf < 4; nf++)
                bfr[nf] = *(const s16x8*)&lB[(wc * 64 + nf * 16 + cl) * 64 + ko];
            #pragma unroll
            for (int mf = 0; mf < MF; mf++)
                #pragma unroll
                for (int nf = 0; nf < 4; nf++)
                    acc[mf][nf] = __builtin_amdgcn_mfma_f32_16x16x32_bf16(af[mf], bfr[nf], acc[mf][nf], 0, 0, 0);
        }
        __syncthreads();
    }
    float* Cp = (float*)Cout + (size_t)part * M * N;
    #pragma unroll
    for (int nf = 0; nf < 4; nf++) {
        const int col = n0 + wc * 64 + nf * 16 + cl;
        const float bv = (EPI == 3) ? 0.0f : bias[col];
        #pragma unroll
        for (int mf = 0; mf < MF; mf++) {
            const int rbase = m0 + wr * (MF * 16) + mf * 16 + rh * 4;
            #pragma unroll
            for (int r = 0; r < 4; r++) {
                float v = acc[mf][nf][r] + bv;
                const size_t off = (size_t)(rbase + r) * N + col;
                if constexpr (EPI == 0) {
                    ((unsigned short*)Cout)[off] = f2bf(v);
                } else if constexpr (EPI == 1) {
                    ((float*)Cout)[off] = v + res[off];
                } else if constexpr (EPI == 2) {
                    v = 0.5f * v * (1.0f + erff(v * 0.70710678118654752f));
                    ((unsigned short*)Cout)[off] = f2bf(v);
                } else {
                    Cp[off] = v;
                }
            }
        }
    }
}

// ---------------- 8-phase 256x256 GEMM (head), f32 out, no bias ----------------
#define PH_CORE(MB) \
    __builtin_amdgcn_s_barrier(); \
    __builtin_amdgcn_s_setprio(1); \
    _Pragma("unroll") \
    for (int nf_ = 0; nf_ < 4; ++nf_) { \
        acc[MB][nf_]   = __builtin_amdgcn_mfma_f32_16x16x32_bf16(af[0][0], bf[nf_][0], acc[MB][nf_], 0, 0, 0); \
        acc[MB][nf_]   = __builtin_amdgcn_mfma_f32_16x16x32_bf16(af[0][1], bf[nf_][1], acc[MB][nf_], 0, 0, 0); \
        acc[MB+1][nf_] = __builtin_amdgcn_mfma_f32_16x16x32_bf16(af[1][0], bf[nf_][0], acc[MB+1][nf_], 0, 0, 0); \
        acc[MB+1][nf_] = __builtin_amdgcn_mfma_f32_16x16x32_bf16(af[1][1], bf[nf_][1], acc[MB+1][nf_], 0, 0, 0); \
    } \
    __builtin_amdgcn_s_setprio(0);

#define PHN(MB) \
    PH_CORE(MB) \
    asm volatile("" ::: "memory"); \
    __builtin_amdgcn_s_barrier(); \
    asm volatile("" ::: "memory");

#define PHW(MB) \
    PH_CORE(MB) \
    asm volatile("s_waitcnt vmcnt(4)" ::: "memory"); \
    __builtin_amdgcn_s_barrier(); \
    asm volatile("" ::: "memory");

__global__ __launch_bounds__(512, 1)
void k_gemm8(const short* __restrict__ A, const short* __restrict__ Bt,
             float* __restrict__ C, int M, int N, int K, int mTiles) {
    __shared__ __align__(16) short lA[2][256 * 64];
    __shared__ __align__(16) short lB[2][256 * 64];
    const int tid = threadIdx.x;
    const int l = tid & 63, w = tid >> 6;
    const int wr = w >> 2, wc = w & 3;
    const int per = gridDim.x >> 3;
    const int s2 = (blockIdx.x & 7) * per + (blockIdx.x >> 3);
    const int nt0 = s2 / mTiles, mt = s2 - nt0 * mTiles;
    const int m0 = mt * 256, n0 = nt0 * 256;
    const int cl = l & 15, rh = l >> 4;

    fx4 acc[8][4] = {};

    const int srow = tid >> 3, sc8 = tid & 7;
    const short* pA[2][2]; const short* pB[2][2];
    #pragma unroll
    for (int hh = 0; hh < 2; ++hh)
        #pragma unroll
        for (int j = 0; j < 2; ++j) {
            const int row = hh * 128 + j * 64 + srow;
            const int cg = (sc8 ^ (row & 7)) << 3;
            pA[hh][j] = A + (size_t)(m0 + row) * K + cg;
            pB[hh][j] = Bt + (size_t)(n0 + row) * K + cg;
        }

    auto stageA = [&](int b, int hh, int kt) {
        #pragma unroll
        for (int j = 0; j < 2; ++j)
            gload16(pA[hh][j] + (kt << 6), &lA[b][(hh * 128 + j * 64 + w * 8) * 64]);
    };
    auto stageB = [&](int b, int hh, int kt) {
        #pragma unroll
        for (int j = 0; j < 2; ++j)
            gload16(pB[hh][j] + (kt << 6), &lB[b][(hh * 128 + j * 64 + w * 8) * 64]);
    };
    auto readA = [&](int b, int mf, int kk) -> s16x8 {
        const int row = wr * 128 + mf * 16 + cl;
        return *(const s16x8*)&lA[b][(row << 6) + (((kk * 4 + rh) ^ (row & 7)) << 3)];
    };
    auto readB = [&](int b, int nf, int kk) -> s16x8 {
        const int row = wc * 64 + nf * 16 + cl;
        return *(const s16x8*)&lB[b][(row << 6) + (((kk * 4 + rh) ^ (row & 7)) << 3)];
    };

    const int NT = K >> 6;
    stageA(0, 0, 0); stageA(0, 1, 0);
    stageB(0, 0, 0); stageB(0, 1, 0);
    stageB(1, 0, 1); stageB(1, 1, 1);
    asm volatile("s_waitcnt vmcnt(4)" ::: "memory");
    __builtin_amdgcn_s_barrier();
    asm volatile("" ::: "memory");

    s16x8 bf[4][2], af[2][2];
    for (int c = 0; c < (NT >> 1); ++c) {
        const int kt = c << 1;
        const int k1 = kt + 1;
        const int k2 = (kt + 2 < NT) ? kt + 2 : NT - 1;
        const int k3 = (kt + 3 < NT) ? kt + 3 : NT - 1;

        #pragma unroll
        for (int nf = 0; nf < 4; ++nf) { bf[nf][0] = readB(0, nf, 0); bf[nf][1] = readB(0, nf, 1); }
        af[0][0] = readA(0, 0, 0); af[0][1] = readA(0, 0, 1);
        af[1][0] = readA(0, 1, 0); af[1][1] = readA(0, 1, 1);
        stageA(1, 0, k1); stageA(1, 1, k1);
        PHN(0)
        af[0][0] = readA(0, 2, 0); af[0][1] = readA(0, 2, 1);
        af[1][0] = readA(0, 3, 0); af[1][1] = readA(0, 3, 1);
        stageB(0, 0, k2);
        PHN(2)
        af[0][0] = readA(0, 4, 0); af[0][1] = readA(0, 4, 1);
        af[1][0] = readA(0, 5, 0); af[1][1] = readA(0, 5, 1);
        stageB(0, 1, k2);
        PHN(4)
        af[0][0] = readA(0, 6, 0); af[0][1] = readA(0, 6, 1);
        af[1][0] = readA(0, 7, 0); af[1][1] = readA(0, 7, 1);
        PHW(6)
        #pragma unroll
        for (int nf = 0; nf < 4; ++nf) { bf[nf][0] = readB(1, nf, 0); bf[nf][1] = readB(1, nf, 1); }
        af[0][0] = readA(1, 0, 0); af[0][1] = readA(1, 0, 1);
        af[1][0] = readA(1, 1, 0); af[1][1] = readA(1, 1, 1);
        stageA(0, 0, k2);
        PHN(0)
        af[0][0] = readA(1, 2, 0); af[0][1] = readA(1, 2, 1);
        af[1][0] = readA(1, 3, 0); af[1][1] = readA(1, 3, 1);
        stageA(0, 1, k2);
        PHN(2)
        af[0][0] = readA(1, 4, 0); af[0][1] = readA(1, 4, 1);
        af[1][0] = readA(1, 5, 0); af[1][1] = readA(1, 5, 1);
        stageB(1, 0, k3);
        PHN(4)
        af[0][0] = readA(1, 6, 0); af[0][1] = readA(1, 6, 1);
        af[1][0] = readA(1, 7, 0); af[1][1] = readA(1, 7, 1);
        stageB(1, 1, k3);
        PHW(6)
    }

    #pragma unroll
    for (int mf = 0; mf < 8; ++mf) {
        const int rbase = m0 + wr * 128 + mf * 16 + rh * 4;
        #pragma unroll
        for (int nf = 0; nf < 4; ++nf) {
            const int col = n0 + wc * 64 + nf * 16 + cl;
            #pragma unroll
            for (int r = 0; r < 4; ++r)
                C[(size_t)(rbase + r) * N + col] = acc[mf][nf][r];
        }
    }
}

// ---------------- fused causal attention: block-shared K/V LDS, dbuf+vmcnt ----------------
// 4 waves, 32 q-rows/wave (2 subtiles at +0 and +64). K tile [64t][64k], V^T tile
// [64hd][64t] staged once per block via gload_lds (linear dest, inv-XOR source),
// double-buffered; counted vmcnt(4); raw barriers. Swapped QK^T + in-lane softmax.
__global__ __launch_bounds__(256) void k_attn(const short* __restrict__ qkv,
                                              const short* __restrict__ vt,
                                              short* __restrict__ y) {
    const int bh = blockIdx.y, qt = blockIdx.x;
    const int b = bh >> 4, h = bh & 15;
    const int tid = threadIdx.x;
    const int w = tid >> 6, l = tid & 63;
    const int cl = l & 15, rh = l >> 4;
    const int qb0 = qt * 128;
    const short* qbase = qkv + (size_t)b * 1024 * 3072 + h * 64;
    const short* kbase = qbase + 1024;
    const short* vbase = vt + (size_t)bh * 64 * 1024;

    __shared__ __align__(16) short kld[2][64][64];
    __shared__ __align__(16) short vld[2][64][64];
    __shared__ __align__(16) short plds[4][32][64];
    char* pbase = (char*)&plds[w][0][0];

    s16x8 qf[2][2];
    #pragma unroll
    for (int n = 0; n < 2; n++)
        #pragma unroll
        for (int kf = 0; kf < 2; kf++)
            qf[n][kf] = *(const s16x8*)&qbase[(size_t)(qb0 + n * 64 + w * 16 + cl) * 3072 + kf * 32 + rh * 8];

    // staging: issue j covers rows j*32 + (tid>>3); chunk tid&7; inv-XOR source
    const int sr = tid >> 3, c8 = tid & 7;
    const short* kp[2]; const short* vp[2];
    #pragma unroll
    for (int j = 0; j < 2; j++) {
        const int row = j * 32 + sr;
        kp[j] = kbase + (size_t)row * 3072 + ((c8 ^ (row & 7)) << 3);
        vp[j] = vbase + (size_t)row * 1024 + ((c8 ^ (row & 7)) << 3);
    }
    auto stageKV = [&](int buf, int t0) {
        gload16(kp[0] + (size_t)t0 * 3072, &kld[buf][w * 8][0]);
        gload16(kp[1] + (size_t)t0 * 3072, &kld[buf][32 + w * 8][0]);
        gload16(vp[0] + t0, &vld[buf][w * 8][0]);
        gload16(vp[1] + t0, &vld[buf][32 + w * 8][0]);
    };
    auto readK = [&](int buf, int m, int kf) -> s16x8 {
        const int row = m * 16 + cl;
        return *(const s16x8*)((const char*)&kld[buf][0][0] + row * 128 + (((kf * 4 + rh) ^ (row & 7)) << 4));
    };
    auto readV = [&](int buf, int mp, int kf) -> s16x8 {
        const int row = mp * 16 + cl;
        return *(const s16x8*)((const char*)&vld[buf][0][0] + row * 128 + (((kf * 4 + rh) ^ (row & 7)) << 4));
    };

    fx4 oacc[4][2] = {};
    float mrow[2] = {-3e38f, -3e38f}, lrow[2] = {0.0f, 0.0f};
    const float SC = 0.125f * 1.44269504088896f;   // scale * log2(e)

    const int ntile = 2 * qt + 2;
    stageKV(0, 0);
    for (int it = 0; it < ntile; it++) {
        const int t0 = it * 64;
        const int buf = it & 1;
        if (it + 1 < ntile) {
            stageKV(buf ^ 1, t0 + 64);
            asm volatile("s_waitcnt vmcnt(4)" ::: "memory");
        } else {
            asm volatile("s_waitcnt vmcnt(0)" ::: "memory");
        }
        __builtin_amdgcn_s_barrier();
        asm volatile("" ::: "memory");

        fx4 s[4][2] = {};
        #pragma unroll
        for (int kf = 0; kf < 2; kf++) {
            s16x8 kfr[4];
            #pragma unroll
            for (int m = 0; m < 4; m++)
                kfr[m] = readK(buf, m, kf);
            #pragma unroll
            for (int m = 0; m < 4; m++)
                #pragma unroll
                for (int n = 0; n < 2; n++)
                    s[m][n] = __builtin_amdgcn_mfma_f32_16x16x32_bf16(kfr[m], qf[n][kf], s[m][n], 0, 0, 0);
        }
        #pragma unroll
        for (int n = 0; n < 2; n++) {
            const int q = qb0 + n * 64 + w * 16 + cl;
            const bool domask = (t0 + 63) > q;
            float tmax = -3e38f;
            #pragma unroll
            for (int m = 0; m < 4; m++)
                #pragma unroll
                for (int r = 0; r < 4; r++) {
                    float v = s[m][n][r] * SC;
                    if (domask && (t0 + m * 16 + rh * 4 + r) > q) v = -3e38f;
                    s[m][n][r] = v;
                    tmax = fmaxf(tmax, v);
                }
            tmax = fmaxf(tmax, __shfl_xor(tmax, 16));
            tmax = fmaxf(tmax, __shfl_xor(tmax, 32));
            const float mnew = fmaxf(mrow[n], tmax);
            const float alpha = exp2f(mrow[n] - mnew);
            mrow[n] = mnew;
            float rsum = 0.0f;
            #pragma unroll
            for (int m = 0; m < 4; m++)
                #pragma unroll
                for (int r = 0; r < 4; r++) {
                    float p = exp2f(s[m][n][r] - mnew);
                    s[m][n][r] = p;
                    rsum += p;
                }
            rsum += __shfl_xor(rsum, 16);
            rsum += __shfl_xor(rsum, 32);
            lrow[n] = lrow[n] * alpha + rsum;
            #pragma unroll
            for (int mp = 0; mp < 4; mp++)
                #pragma unroll
                for (int r = 0; r < 4; r++)
                    oacc[mp][n][r] *= alpha;
        }
        // pack P -> per-wave LDS [q][k], XOR swizzle
        #pragma unroll
        for (int n = 0; n < 2; n++) {
            const int qr = n * 16 + cl;
            const int sw = (qr & 7) << 4;
            #pragma unroll
            for (int m = 0; m < 4; m++) {
                uint2 pk2;
                pk2.x = cvtpk(s[m][n][0], s[m][n][1]);
                pk2.y = cvtpk(s[m][n][2], s[m][n][3]);
                const int off = qr * 128 + ((m * 32 + rh * 8) ^ sw);
                *(uint2*)(pbase + off) = pk2;
            }
        }
        s16x8 pb2[2][2];
        #pragma unroll
        for (int n = 0; n < 2; n++) {
            const int qr = n * 16 + cl;
            const int sw = (qr & 7) << 4;
            #pragma unroll
            for (int kf = 0; kf < 2; kf++)
                pb2[n][kf] = *(const s16x8*)(pbase + qr * 128 + ((kf * 64 + rh * 16) ^ sw));
        }
        s16x8 vf[4][2];
        #pragma unroll
        for (int mp = 0; mp < 4; mp++)
            #pragma unroll
            for (int kf = 0; kf < 2; kf++)
                vf[mp][kf] = readV(buf, mp, kf);
        #pragma unroll
        for (int mp = 0; mp < 4; mp++)
            #pragma unroll
            for (int n = 0; n < 2; n++)
                #pragma unroll
                for (int kf = 0; kf < 2; kf++)
                    oacc[mp][n] = __builtin_amdgcn_mfma_f32_16x16x32_bf16(vf[mp][kf], pb2[n][kf], oacc[mp][n], 0, 0, 0);
        asm volatile("" ::: "memory");
        __builtin_amdgcn_s_barrier();
        asm volatile("" ::: "memory");
    }
    #pragma unroll
    for (int n = 0; n < 2; n++) {
        const float inv = 1.0f / lrow[n];
        const int q = qb0 + n * 64 + w * 16 + cl;
        #pragma unroll
        for (int mp = 0; mp < 4; mp++) {
            uint2 pk2;
            pk2.x = cvtpk(oacc[mp][n][0] * inv, oacc[mp][n][1] * inv);
            pk2.y = cvtpk(oacc[mp][n][2] * inv, oacc[mp][n][3] * inv);
            *(uint2*)&y[(size_t)(b * 1024 + q) * 1024 + h * 64 + mp * 16 + rh * 4] = pk2;
        }
    }
}

// ---------------- host launcher ----------------
extern "C" void kernel_launch(void* const* d_in, const int* in_sizes, int n_in,
                              void* d_out, int out_size, void* d_ws, size_t ws_size,
                              hipStream_t stream) {
    const int*   idx   = (const int*)d_in[0];
    const float* tok   = (const float*)d_in[1];
    const float* pos   = (const float*)d_in[2];
    const float* ln1w  = (const float*)d_in[3];
    const float* ln1b  = (const float*)d_in[4];
    const float* Wq    = (const float*)d_in[5];
    const float* bq    = (const float*)d_in[6];
    const float* Wk    = (const float*)d_in[7];
    const float* bk    = (const float*)d_in[8];
    const float* Wv    = (const float*)d_in[9];
    const float* bv    = (const float*)d_in[10];
    const float* Wo    = (const float*)d_in[11];
    const float* bo    = (const float*)d_in[12];
    const float* ln2w  = (const float*)d_in[13];
    const float* ln2b  = (const float*)d_in[14];
    const float* W1    = (const float*)d_in[15];
    const float* b1    = (const float*)d_in[16];
    const float* W2    = (const float*)d_in[17];
    const float* b2    = (const float*)d_in[18];
    const float* lnfw  = (const float*)d_in[19];
    const float* lnfb  = (const float*)d_in[20];
    const float* headw = (const float*)d_in[21];

    char* ws = (char*)d_ws;
    size_t off = 0;
    auto nalloc = [&](size_t bytes) -> char* {
        char* p = ws + off;
        off = (off + bytes + 255) & ~(size_t)255;
        return p;
    };
    float* x     = (float*)nalloc((size_t)2048 * 1024 * 4);
    short* h     = (short*)nalloc((size_t)2048 * 1024 * 2);
    short* qkv   = (short*)nalloc((size_t)2048 * 3072 * 2);
    short* vtb   = (short*)nalloc((size_t)32 * 64 * 1024 * 2);
    short* y     = (short*)nalloc((size_t)2048 * 1024 * 2);
    short* u     = (short*)nalloc((size_t)2048 * 4096 * 2);
    float* mpart = (float*)nalloc((size_t)4 * 2048 * 1024 * 4);
    short* wqkv  = (short*)nalloc((size_t)4 * 3072 * 1024 * 2);
    short* wo    = (short*)nalloc((size_t)4 * 1024 * 1024 * 2);
    short* w1    = (short*)nalloc((size_t)4 * 4096 * 1024 * 2);
    short* w2    = (short*)nalloc((size_t)4 * 1024 * 4096 * 2);
    short* wh    = (short*)nalloc((size_t)32000 * 1024 * 2);
    float* bqkv  = (float*)nalloc((size_t)4 * 3072 * 4);

    // ---- weight prep ----
    k_bcat<<<48, 256, 0, stream>>>(bq, bk, bv, bqkv);
    k_tconv_all<<<20288, 256, 0, stream>>>(Wq, Wk, Wv, Wo, W1, W2, headw,
                                           wqkv, wo, w1, w2, wh);

    // ---- forward ----
    k_embedln<<<2048, 256, 0, stream>>>(idx, tok, pos, ln1w, ln1b, x, h);
    for (int lyr = 0; lyr < 4; lyr++) {
        k_gemm<2, 0><<<768, 256, 0, stream>>>(h, wqkv + (size_t)lyr * 3072 * 1024, bqkv + lyr * 3072,
                                              nullptr, qkv, 2048, 3072, 1024, 1024, 32, 1);
        k_vt<<<dim3(16, 32), 256, 0, stream>>>(qkv, vtb);
        k_attn<<<dim3(8, 32), 256, 0, stream>>>(qkv, vtb, y);
        k_gemm<2, 1><<<256, 256, 0, stream>>>(y, wo + (size_t)lyr * 1024 * 1024, bo + lyr * 1024,
                                              x, x, 2048, 1024, 1024, 1024, 32, 1);
        k_ln<<<2048, 256, 0, stream>>>(x, ln2w + lyr * 1024, ln2b + lyr * 1024, h);
        k_gemm<2, 2><<<1024, 256, 0, stream>>>(h, w1 + (size_t)lyr * 4194304, b1 + lyr * 4096,
                                               nullptr, u, 2048, 4096, 1024, 1024, 32, 1);
        k_gemm<2, 3><<<1024, 256, 0, stream>>>(u, w2 + (size_t)lyr * 4194304, nullptr,
                                               nullptr, mpart, 2048, 1024, 4096, 1024, 32, 4);
        const float* nw = (lyr < 3) ? (ln1w + (lyr + 1) * 1024) : lnfw;
        const float* nb = (lyr < 3) ? (ln1b + (lyr + 1) * 1024) : lnfb;
        k_redln<<<2048, 256, 0, stream>>>(mpart, b2 + lyr * 1024, x, nw, nb, h);
    }
    k_gemm8<<<1000, 512, 0, stream>>>(h, wh, (float*)d_out, 2048, 32000, 1024, 8);
    (void)in_sizes; (void)n_in; (void)out_size; (void)ws_size;
}

// Round 9
// 970.404 us; speedup vs baseline: 1.1210x; 1.0413x over previous
//
#include <hip/hip_runtime.h>
#include <hip/hip_bf16.h>

// GPT forward: B=2, T=1024, D=1024, H=16, HD=64, L=4, V=32000
// R9: attn reverted to R6 version (global K/V reads — L2-resident, staging was
//     overhead, Common-mistake #7). MLP1/MLP2 at MF=4 (128^2 tiles, 512 blocks
//     = 2 blocks/CU exactly). QKV/O-proj stay MF=2. Head unchanged.

typedef __attribute__((ext_vector_type(8))) short s16x8;
typedef __attribute__((ext_vector_type(4))) float fx4;

__device__ __forceinline__ unsigned short f2bf(float f) {
    union { float f; unsigned int u; } v; v.f = f;
    unsigned int r = v.u + 0x7FFFu + ((v.u >> 16) & 1u);
    return (unsigned short)(r >> 16);
}

__device__ __forceinline__ void gload16(const short* g, short* l) {
    __builtin_amdgcn_global_load_lds((const __attribute__((address_space(1))) void*)g,
                                     (__attribute__((address_space(3))) void*)l, 16, 0, 0);
}

__device__ __forceinline__ unsigned cvtpk(float a, float b) {
    unsigned r;
    asm("v_cvt_pk_bf16_f32 %0, %1, %2" : "=v"(r) : "v"(a), "v"(b));
    return r;
}

// ---------------- embed + LN fused (row-local) ----------------
__global__ __launch_bounds__(256) void k_embedln(const int* __restrict__ idx,
                                                 const float* __restrict__ tok,
                                                 const float* __restrict__ pos,
                                                 const float* __restrict__ lw,
                                                 const float* __restrict__ lb,
                                                 float* __restrict__ x,
                                                 short* __restrict__ out) {
    int r = blockIdx.x;
    int t = r & 1023;
    int tokid = idx[r];
    int tid = threadIdx.x;
    float4 v = ((const float4*)(tok + (size_t)tokid * 1024))[tid];
    float4 vp = ((const float4*)(pos + (size_t)t * 1024))[tid];
    v.x += vp.x; v.y += vp.y; v.z += vp.z; v.w += vp.w;
    ((float4*)(x + (size_t)r * 1024))[tid] = v;
    float s = v.x + v.y + v.z + v.w;
    float ss = v.x*v.x + v.y*v.y + v.z*v.z + v.w*v.w;
    __shared__ float red[8];
    #pragma unroll
    for (int off = 32; off; off >>= 1) { s += __shfl_down(s, off); ss += __shfl_down(ss, off); }
    int wid = tid >> 6;
    if ((tid & 63) == 0) { red[wid] = s; red[4 + wid] = ss; }
    __syncthreads();
    s = red[0] + red[1] + red[2] + red[3];
    ss = red[4] + red[5] + red[6] + red[7];
    float mean = s * (1.0f / 1024.0f);
    float var = ss * (1.0f / 1024.0f) - mean * mean;
    float rstd = rsqrtf(var + 1e-5f);
    float4 wv = ((const float4*)lw)[tid];
    float4 bv = ((const float4*)lb)[tid];
    union { unsigned short us[4]; unsigned long long ll; } pk;
    pk.us[0] = f2bf((v.x - mean) * rstd * wv.x + bv.x);
    pk.us[1] = f2bf((v.y - mean) * rstd * wv.y + bv.y);
    pk.us[2] = f2bf((v.z - mean) * rstd * wv.z + bv.z);
    pk.us[3] = f2bf((v.w - mean) * rstd * wv.w + bv.w);
    ((unsigned long long*)(out + (size_t)r * 1024))[tid] = pk.ll;
}

// ---------------- layernorm (row of 1024), bf16 out ----------------
__global__ __launch_bounds__(256) void k_ln(const float* __restrict__ x,
                                            const float* __restrict__ w,
                                            const float* __restrict__ b,
                                            short* __restrict__ out) {
    int r = blockIdx.x;
    int tid = threadIdx.x;
    float4 v = ((const float4*)(x + (size_t)r * 1024))[tid];
    float s = v.x + v.y + v.z + v.w;
    float ss = v.x*v.x + v.y*v.y + v.z*v.z + v.w*v.w;
    __shared__ float red[8];
    #pragma unroll
    for (int off = 32; off; off >>= 1) { s += __shfl_down(s, off); ss += __shfl_down(ss, off); }
    int wid = tid >> 6;
    if ((tid & 63) == 0) { red[wid] = s; red[4 + wid] = ss; }
    __syncthreads();
    s = red[0] + red[1] + red[2] + red[3];
    ss = red[4] + red[5] + red[6] + red[7];
    float mean = s * (1.0f / 1024.0f);
    float var = ss * (1.0f / 1024.0f) - mean * mean;
    float rstd = rsqrtf(var + 1e-5f);
    float4 wv = ((const float4*)w)[tid];
    float4 bv = ((const float4*)b)[tid];
    union { unsigned short us[4]; unsigned long long ll; } pk;
    pk.us[0] = f2bf((v.x - mean) * rstd * wv.x + bv.x);
    pk.us[1] = f2bf((v.y - mean) * rstd * wv.y + bv.y);
    pk.us[2] = f2bf((v.z - mean) * rstd * wv.z + bv.z);
    pk.us[3] = f2bf((v.w - mean) * rstd * wv.w + bv.w);
    ((unsigned long long*)(out + (size_t)r * 1024))[tid] = pk.ll;
}

// ---------------- splitK reduce + bias + residual + LN fused ----------------
__global__ __launch_bounds__(256) void k_redln(const float* __restrict__ part,
                                               const float* __restrict__ bias,
                                               float* __restrict__ x,
                                               const float* __restrict__ lw,
                                               const float* __restrict__ lb,
                                               short* __restrict__ out) {
    const size_t PS = (size_t)2048 * 1024;
    const int r = blockIdx.x;
    const int tid = threadIdx.x;
    const size_t base = (size_t)r * 1024 + tid * 4;
    float4 a = *(const float4*)(part + base);
    float4 b = *(const float4*)(part + PS + base);
    float4 c = *(const float4*)(part + 2 * PS + base);
    float4 d = *(const float4*)(part + 3 * PS + base);
    float4 v = *(const float4*)(x + base);
    float4 bb = *(const float4*)(bias + tid * 4);
    v.x += a.x + b.x + c.x + d.x + bb.x;
    v.y += a.y + b.y + c.y + d.y + bb.y;
    v.z += a.z + b.z + c.z + d.z + bb.z;
    v.w += a.w + b.w + c.w + d.w + bb.w;
    *(float4*)(x + base) = v;
    float s = v.x + v.y + v.z + v.w;
    float ss = v.x*v.x + v.y*v.y + v.z*v.z + v.w*v.w;
    __shared__ float red[8];
    #pragma unroll
    for (int off = 32; off; off >>= 1) { s += __shfl_down(s, off); ss += __shfl_down(ss, off); }
    int wid = tid >> 6;
    if ((tid & 63) == 0) { red[wid] = s; red[4 + wid] = ss; }
    __syncthreads();
    s = red[0] + red[1] + red[2] + red[3];
    ss = red[4] + red[5] + red[6] + red[7];
    float mean = s * (1.0f / 1024.0f);
    float var = ss * (1.0f / 1024.0f) - mean * mean;
    float rstd = rsqrtf(var + 1e-5f);
    float4 wv = ((const float4*)lw)[tid];
    float4 bv = ((const float4*)lb)[tid];
    union { unsigned short us[4]; unsigned long long ll; } pk;
    pk.us[0] = f2bf((v.x - mean) * rstd * wv.x + bv.x);
    pk.us[1] = f2bf((v.y - mean) * rstd * wv.y + bv.y);
    pk.us[2] = f2bf((v.z - mean) * rstd * wv.z + bv.z);
    pk.us[3] = f2bf((v.w - mean) * rstd * wv.w + bv.w);
    ((unsigned long long*)(out + (size_t)r * 1024))[tid] = pk.ll;
}

// ---------------- batched transpose+convert: all weights, one dispatch ----------------
__global__ __launch_bounds__(256) void k_tconv_all(
        const float* __restrict__ Wq, const float* __restrict__ Wk,
        const float* __restrict__ Wv, const float* __restrict__ Wo,
        const float* __restrict__ W1, const float* __restrict__ W2,
        const float* __restrict__ Wh,
        short* __restrict__ wqkv, short* __restrict__ wo,
        short* __restrict__ w1, short* __restrict__ w2, short* __restrict__ wh) {
    const int bid = blockIdx.x;
    const float* src; short* dst; int K, N, tile;
    if (bid < 4096) {
        int seg = bid >> 10;
        int r = bid & 1023;
        int l = r >> 8; tile = r & 255;
        K = 1024; N = 1024;
        if (seg == 0)      { src = Wq + (size_t)l * 1048576; dst = wqkv + (size_t)l * 3145728; }
        else if (seg == 1) { src = Wk + (size_t)l * 1048576; dst = wqkv + (size_t)l * 3145728 + 1048576; }
        else if (seg == 2) { src = Wv + (size_t)l * 1048576; dst = wqkv + (size_t)l * 3145728 + 2097152; }
        else               { src = Wo + (size_t)l * 1048576; dst = wo + (size_t)l * 1048576; }
    } else if (bid < 8192) {
        int r = bid - 4096; int l = r >> 10; tile = r & 1023;
        K = 1024; N = 4096; src = W1 + (size_t)l * 4194304; dst = w1 + (size_t)l * 4194304;
    } else if (bid < 12288) {
        int r = bid - 8192; int l = r >> 10; tile = r & 1023;
        K = 4096; N = 1024; src = W2 + (size_t)l * 4194304; dst = w2 + (size_t)l * 4194304;
    } else {
        tile = bid - 12288; K = 1024; N = 32000; src = Wh; dst = wh;
    }
    const int nTiles = N >> 6;
    const int kt = tile / nTiles, ntl = tile - kt * nTiles;
    const int n0 = ntl * 64, k0 = kt * 64;

    __shared__ float tl[64][65];
    const int tid = threadIdx.x;
    const int c4 = tid & 15, rr = tid >> 4;
    #pragma unroll
    for (int j = 0; j < 4; j++) {
        int row = rr + j * 16;
        float4 vv = *(const float4*)(src + (size_t)(k0 + row) * N + n0 + c4 * 4);
        tl[row][c4*4+0] = vv.x; tl[row][c4*4+1] = vv.y;
        tl[row][c4*4+2] = vv.z; tl[row][c4*4+3] = vv.w;
    }
    __syncthreads();
    const int c8 = tid & 7, r2 = tid >> 3;
    #pragma unroll
    for (int j = 0; j < 2; j++) {
        int nrow = r2 + j * 32;
        union { unsigned short us[8]; s16x8 v; } pk;
        #pragma unroll
        for (int e = 0; e < 8; e++) pk.us[e] = f2bf(tl[c8*8+e][nrow]);
        *(s16x8*)&dst[(size_t)(n0 + nrow) * K + k0 + c8 * 8] = pk.v;
    }
}

// ---------------- concat qkv bias: [L][3072] ----------------
__global__ __launch_bounds__(256) void k_bcat(const float* __restrict__ bq,
                                              const float* __restrict__ bk,
                                              const float* __restrict__ bv,
                                              float* __restrict__ o) {
    int i = blockIdx.x * 256 + threadIdx.x;
    int l = i / 3072, c = i % 3072;
    float v = (c < 1024) ? bq[l*1024 + c] : ((c < 2048) ? bk[l*1024 + c - 1024] : bv[l*1024 + c - 2048]);
    o[i] = v;
}

// ---------------- V transpose per (b,h) ----------------
__global__ __launch_bounds__(256) void k_vt(const short* __restrict__ qkv, short* __restrict__ vt) {
    int bh = blockIdx.y, b = bh >> 4, h = bh & 15;
    int t0 = blockIdx.x * 64;
    __shared__ short tile[64][72];
    int tid = threadIdx.x;
    int ch = tid & 7, rr = tid >> 3;
    const short* src = qkv + (size_t)b * 1024 * 3072 + 2048 + h * 64;
    #pragma unroll
    for (int j = 0; j < 2; j++) {
        int t = rr + j * 32;
        s16x8 v = *(const s16x8*)&src[(size_t)(t0 + t) * 3072 + ch * 8];
        *(s16x8*)&tile[t][ch * 8] = v;
    }
    __syncthreads();
    #pragma unroll
    for (int j = 0; j < 2; j++) {
        int hd = rr + j * 32;
        union { short ss[8]; s16x8 v; } pk;
        #pragma unroll
        for (int e = 0; e < 8; e++) pk.ss[e] = tile[ch * 8 + e][hd];
        *(s16x8*)&vt[(size_t)(bh * 64 + hd) * 1024 + t0 + ch * 8] = pk.v;
    }
}

// ---------------- 128-class GEMM (m97 structure), EPI + split-K support ----------------
// EPI: 0 = bias->bf16; 1 = f32 + residual; 2 = bias+GELU->bf16; 3 = f32 partial (no bias)
template<int MF, int EPI>
__global__ __launch_bounds__(256) void k_gemm(const short* __restrict__ A, const short* __restrict__ Bt,
                                              const float* bias, const float* res, void* Cout,
                                              int M, int N, int Kstride, int kLen,
                                              int mTiles, int nParts) {
    constexpr int BM = MF * 32;
    constexpr int IA = BM / 32;
    __shared__ __align__(16) short lA[BM * 64];
    __shared__ __align__(16) short lB[128 * 64];
    const int tid = threadIdx.x;
    const int l = tid & 63, w = tid >> 6;
    const int wr = w >> 1, wc = w & 1;
    const int per = gridDim.x >> 3;
    const int s2 = (blockIdx.x & 7) * per + (blockIdx.x >> 3);
    const int totPerN = mTiles * nParts;
    const int nt = s2 / totPerN;
    const int rem = s2 - nt * totPerN;
    const int part = rem / mTiles, mt = rem - part * mTiles;
    const int k0 = part * kLen;
    const int m0 = mt * BM, n0 = nt * 128;
    const int cl = l & 15, rh = l >> 4;
    fx4 acc[MF][4] = {};

    const int lr = l >> 3, c8 = l & 7;
    const short* pa[IA];
    const short* pb[4];
    #pragma unroll
    for (int j = 0; j < IA; j++) {
        const int row = w * (BM / 4) + j * 8 + lr;
        pa[j] = A + (size_t)(m0 + row) * Kstride + k0 + ((c8 ^ (row & 7)) << 3);
    }
    #pragma unroll
    for (int j = 0; j < 4; j++) {
        const int row = w * 32 + j * 8 + lr;
        pb[j] = Bt + (size_t)(n0 + row) * Kstride + k0 + ((c8 ^ (row & 7)) << 3);
    }

    for (int kt = 0; kt < kLen; kt += 64) {
        #pragma unroll
        for (int j = 0; j < IA; j++)
            gload16(pa[j] + kt, &lA[(w * (BM / 4) + j * 8) * 64]);
        #pragma unroll
        for (int j = 0; j < 4; j++)
            gload16(pb[j] + kt, &lB[(w * 32 + j * 8) * 64]);
        __syncthreads();
        #pragma unroll
        for (int kk = 0; kk < 2; kk++) {
            s16x8 af[MF], bfr[4];
            const int kc = kk * 4 + rh;
            const int ko = (kc ^ (cl & 7)) * 8;
            #pragma unroll
            for (int mf = 0; mf < MF; mf++)
                af[mf] = *(const s16x8*)&lA[(wr * (MF * 16) + mf * 16 + cl) * 64 + ko];
            #pragma unroll
            for (int nf = 0; nf < 4; nf++)
                bfr[nf] = *(const s16x8*)&lB[(wc * 64 + nf * 16 + cl) * 64 + ko];
            #pragma unroll
            for (int mf = 0; mf < MF; mf++)
                #pragma unroll
                for (int nf = 0; nf < 4; nf++)
                    acc[mf][nf] = __builtin_amdgcn_mfma_f32_16x16x32_bf16(af[mf], bfr[nf], acc[mf][nf], 0, 0, 0);
        }
        __syncthreads();
    }
    float* Cp = (float*)Cout + (size_t)part * M * N;
    #pragma unroll
    for (int nf = 0; nf < 4; nf++) {
        const int col = n0 + wc * 64 + nf * 16 + cl;
        const float bv = (EPI == 3) ? 0.0f : bias[col];
        #pragma unroll
        for (int mf = 0; mf < MF; mf++) {
            const int rbase = m0 + wr * (MF * 16) + mf * 16 + rh * 4;
            #pragma unroll
            for (int r = 0; r < 4; r++) {
                float v = acc[mf][nf][r] + bv;
                const size_t off = (size_t)(rbase + r) * N + col;
                if constexpr (EPI == 0) {
                    ((unsigned short*)Cout)[off] = f2bf(v);
                } else if constexpr (EPI == 1) {
                    ((float*)Cout)[off] = v + res[off];
                } else if constexpr (EPI == 2) {
                    v = 0.5f * v * (1.0f + erff(v * 0.70710678118654752f));
                    ((unsigned short*)Cout)[off] = f2bf(v);
                } else {
                    Cp[off] = v;
                }
            }
        }
    }
}

// ---------------- 8-phase 256x256 GEMM (head), f32 out, no bias ----------------
#define PH_CORE(MB) \
    __builtin_amdgcn_s_barrier(); \
    __builtin_amdgcn_s_setprio(1); \
    _Pragma("unroll") \
    for (int nf_ = 0; nf_ < 4; ++nf_) { \
        acc[MB][nf_]   = __builtin_amdgcn_mfma_f32_16x16x32_bf16(af[0][0], bf[nf_][0], acc[MB][nf_], 0, 0, 0); \
        acc[MB][nf_]   = __builtin_amdgcn_mfma_f32_16x16x32_bf16(af[0][1], bf[nf_][1], acc[MB][nf_], 0, 0, 0); \
        acc[MB+1][nf_] = __builtin_amdgcn_mfma_f32_16x16x32_bf16(af[1][0], bf[nf_][0], acc[MB+1][nf_], 0, 0, 0); \
        acc[MB+1][nf_] = __builtin_amdgcn_mfma_f32_16x16x32_bf16(af[1][1], bf[nf_][1], acc[MB+1][nf_], 0, 0, 0); \
    } \
    __builtin_amdgcn_s_setprio(0);

#define PHN(MB) \
    PH_CORE(MB) \
    asm volatile("" ::: "memory"); \
    __builtin_amdgcn_s_barrier(); \
    asm volatile("" ::: "memory");

#define PHW(MB) \
    PH_CORE(MB) \
    asm volatile("s_waitcnt vmcnt(4)" ::: "memory"); \
    __builtin_amdgcn_s_barrier(); \
    asm volatile("" ::: "memory");

__global__ __launch_bounds__(512, 1)
void k_gemm8(const short* __restrict__ A, const short* __restrict__ Bt,
             float* __restrict__ C, int M, int N, int K, int mTiles) {
    __shared__ __align__(16) short lA[2][256 * 64];
    __shared__ __align__(16) short lB[2][256 * 64];
    const int tid = threadIdx.x;
    const int l = tid & 63, w = tid >> 6;
    const int wr = w >> 2, wc = w & 3;
    const int per = gridDim.x >> 3;
    const int s2 = (blockIdx.x & 7) * per + (blockIdx.x >> 3);
    const int nt0 = s2 / mTiles, mt = s2 - nt0 * mTiles;
    const int m0 = mt * 256, n0 = nt0 * 256;
    const int cl = l & 15, rh = l >> 4;

    fx4 acc[8][4] = {};

    const int srow = tid >> 3, sc8 = tid & 7;
    const short* pA[2][2]; const short* pB[2][2];
    #pragma unroll
    for (int hh = 0; hh < 2; ++hh)
        #pragma unroll
        for (int j = 0; j < 2; ++j) {
            const int row = hh * 128 + j * 64 + srow;
            const int cg = (sc8 ^ (row & 7)) << 3;
            pA[hh][j] = A + (size_t)(m0 + row) * K + cg;
            pB[hh][j] = Bt + (size_t)(n0 + row) * K + cg;
        }

    auto stageA = [&](int b, int hh, int kt) {
        #pragma unroll
        for (int j = 0; j < 2; ++j)
            gload16(pA[hh][j] + (kt << 6), &lA[b][(hh * 128 + j * 64 + w * 8) * 64]);
    };
    auto stageB = [&](int b, int hh, int kt) {
        #pragma unroll
        for (int j = 0; j < 2; ++j)
            gload16(pB[hh][j] + (kt << 6), &lB[b][(hh * 128 + j * 64 + w * 8) * 64]);
    };
    auto readA = [&](int b, int mf, int kk) -> s16x8 {
        const int row = wr * 128 + mf * 16 + cl;
        return *(const s16x8*)&lA[b][(row << 6) + (((kk * 4 + rh) ^ (row & 7)) << 3)];
    };
    auto readB = [&](int b, int nf, int kk) -> s16x8 {
        const int row = wc * 64 + nf * 16 + cl;
        return *(const s16x8*)&lB[b][(row << 6) + (((kk * 4 + rh) ^ (row & 7)) << 3)];
    };

    const int NT = K >> 6;
    stageA(0, 0, 0); stageA(0, 1, 0);
    stageB(0, 0, 0); stageB(0, 1, 0);
    stageB(1, 0, 1); stageB(1, 1, 1);
    asm volatile("s_waitcnt vmcnt(4)" ::: "memory");
    __builtin_amdgcn_s_barrier();
    asm volatile("" ::: "memory");

    s16x8 bf[4][2], af[2][2];
    for (int c = 0; c < (NT >> 1); ++c) {
        const int kt = c << 1;
        const int k1 = kt + 1;
        const int k2 = (kt + 2 < NT) ? kt + 2 : NT - 1;
        const int k3 = (kt + 3 < NT) ? kt + 3 : NT - 1;

        #pragma unroll
        for (int nf = 0; nf < 4; ++nf) { bf[nf][0] = readB(0, nf, 0); bf[nf][1] = readB(0, nf, 1); }
        af[0][0] = readA(0, 0, 0); af[0][1] = readA(0, 0, 1);
        af[1][0] = readA(0, 1, 0); af[1][1] = readA(0, 1, 1);
        stageA(1, 0, k1); stageA(1, 1, k1);
        PHN(0)
        af[0][0] = readA(0, 2, 0); af[0][1] = readA(0, 2, 1);
        af[1][0] = readA(0, 3, 0); af[1][1] = readA(0, 3, 1);
        stageB(0, 0, k2);
        PHN(2)
        af[0][0] = readA(0, 4, 0); af[0][1] = readA(0, 4, 1);
        af[1][0] = readA(0, 5, 0); af[1][1] = readA(0, 5, 1);
        stageB(0, 1, k2);
        PHN(4)
        af[0][0] = readA(0, 6, 0); af[0][1] = readA(0, 6, 1);
        af[1][0] = readA(0, 7, 0); af[1][1] = readA(0, 7, 1);
        PHW(6)
        #pragma unroll
        for (int nf = 0; nf < 4; ++nf) { bf[nf][0] = readB(1, nf, 0); bf[nf][1] = readB(1, nf, 1); }
        af[0][0] = readA(1, 0, 0); af[0][1] = readA(1, 0, 1);
        af[1][0] = readA(1, 1, 0); af[1][1] = readA(1, 1, 1);
        stageA(0, 0, k2);
        PHN(0)
        af[0][0] = readA(1, 2, 0); af[0][1] = readA(1, 2, 1);
        af[1][0] = readA(1, 3, 0); af[1][1] = readA(1, 3, 1);
        stageA(0, 1, k2);
        PHN(2)
        af[0][0] = readA(1, 4, 0); af[0][1] = readA(1, 4, 1);
        af[1][0] = readA(1, 5, 0); af[1][1] = readA(1, 5, 1);
        stageB(1, 0, k3);
        PHN(4)
        af[0][0] = readA(1, 6, 0); af[0][1] = readA(1, 6, 1);
        af[1][0] = readA(1, 7, 0); af[1][1] = readA(1, 7, 1);
        stageB(1, 1, k3);
        PHW(6)
    }

    #pragma unroll
    for (int mf = 0; mf < 8; ++mf) {
        const int rbase = m0 + wr * 128 + mf * 16 + rh * 4;
        #pragma unroll
        for (int nf = 0; nf < 4; ++nf) {
            const int col = n0 + wc * 64 + nf * 16 + cl;
            #pragma unroll
            for (int r = 0; r < 4; ++r)
                C[(size_t)(rbase + r) * N + col] = acc[mf][nf][r];
        }
    }
}

// ---------------- fused causal attention (R6 version): swapped QK^T, global K/V ----------------
__global__ __launch_bounds__(256) void k_attn(const short* __restrict__ qkv,
                                              const short* __restrict__ vt,
                                              short* __restrict__ y) {
    const int bh = blockIdx.y, qt = blockIdx.x;
    const int b = bh >> 4, h = bh & 15;
    const int w = threadIdx.x >> 6, l = threadIdx.x & 63;
    const int cl = l & 15, rh = l >> 4;
    const int q0 = qt * 128 + w * 32;
    const short* qbase = qkv + (size_t)b * 1024 * 3072 + h * 64;
    const short* kbase = qbase + 1024;
    const short* vbase = vt + (size_t)bh * 64 * 1024;
    __shared__ __align__(16) short plds[4][32][64];
    char* pbase = (char*)&plds[w][0][0];

    s16x8 qf[2][2];
    #pragma unroll
    for (int n = 0; n < 2; n++)
        #pragma unroll
        for (int kf = 0; kf < 2; kf++)
            qf[n][kf] = *(const s16x8*)&qbase[(size_t)(q0 + n * 16 + cl) * 3072 + kf * 32 + rh * 8];

    fx4 oacc[4][2] = {};
    float mrow[2] = {-3e38f, -3e38f}, lrow[2] = {0.0f, 0.0f};
    const float SC = 0.125f * 1.44269504088896f;   // scale * log2(e): exp2-domain

    const int ntile = (q0 + 95) >> 6;
    for (int it = 0; it < ntile; it++) {
        const int t0 = it * 64;
        fx4 s[4][2] = {};
        #pragma unroll
        for (int kf = 0; kf < 2; kf++) {
            s16x8 kfr[4];
            #pragma unroll
            for (int m = 0; m < 4; m++)
                kfr[m] = *(const s16x8*)&kbase[(size_t)(t0 + m * 16 + cl) * 3072 + kf * 32 + rh * 8];
            #pragma unroll
            for (int m = 0; m < 4; m++)
                #pragma unroll
                for (int n = 0; n < 2; n++)
                    s[m][n] = __builtin_amdgcn_mfma_f32_16x16x32_bf16(kfr[m], qf[n][kf], s[m][n], 0, 0, 0);
        }
        const bool domask = (t0 + 63) > q0;
        #pragma unroll
        for (int n = 0; n < 2; n++) {
            const int q = q0 + n * 16 + cl;
            float tmax = -3e38f;
            #pragma unroll
            for (int m = 0; m < 4; m++)
                #pragma unroll
                for (int r = 0; r < 4; r++) {
                    float v = s[m][n][r] * SC;
                    if (domask && (t0 + m * 16 + rh * 4 + r) > q) v = -3e38f;
                    s[m][n][r] = v;
                    tmax = fmaxf(tmax, v);
                }
            tmax = fmaxf(tmax, __shfl_xor(tmax, 16));
            tmax = fmaxf(tmax, __shfl_xor(tmax, 32));
            const float mnew = fmaxf(mrow[n], tmax);
            const float alpha = exp2f(mrow[n] - mnew);
            mrow[n] = mnew;
            float rsum = 0.0f;
            #pragma unroll
            for (int m = 0; m < 4; m++)
                #pragma unroll
                for (int r = 0; r < 4; r++) {
                    float p = exp2f(s[m][n][r] - mnew);
                    s[m][n][r] = p;
                    rsum += p;
                }
            rsum += __shfl_xor(rsum, 16);
            rsum += __shfl_xor(rsum, 32);
            lrow[n] = lrow[n] * alpha + rsum;
            #pragma unroll
            for (int mp = 0; mp < 4; mp++)
                #pragma unroll
                for (int r = 0; r < 4; r++)
                    oacc[mp][n][r] *= alpha;
        }
        // pack P -> per-wave LDS [q][k], b64 writes, XOR swizzle on k-bytes
        #pragma unroll
        for (int n = 0; n < 2; n++) {
            const int qr = n * 16 + cl;
            const int sw = (qr & 7) << 4;
            #pragma unroll
            for (int m = 0; m < 4; m++) {
                uint2 pk2;
                pk2.x = cvtpk(s[m][n][0], s[m][n][1]);
                pk2.y = cvtpk(s[m][n][2], s[m][n][3]);
                const int off = qr * 128 + ((m * 32 + rh * 8) ^ sw);
                *(uint2*)(pbase + off) = pk2;
            }
        }
        s16x8 pb2[2][2];
        #pragma unroll
        for (int n = 0; n < 2; n++) {
            const int qr = n * 16 + cl;
            const int sw = (qr & 7) << 4;
            #pragma unroll
            for (int kf = 0; kf < 2; kf++)
                pb2[n][kf] = *(const s16x8*)(pbase + qr * 128 + ((kf * 64 + rh * 16) ^ sw));
        }
        s16x8 vf[4][2];
        #pragma unroll
        for (int mp = 0; mp < 4; mp++)
            #pragma unroll
            for (int kf = 0; kf < 2; kf++)
                vf[mp][kf] = *(const s16x8*)&vbase[(size_t)(mp * 16 + cl) * 1024 + t0 + kf * 32 + rh * 8];
        #pragma unroll
        for (int mp = 0; mp < 4; mp++)
            #pragma unroll
            for (int n = 0; n < 2; n++)
                #pragma unroll
                for (int kf = 0; kf < 2; kf++)
                    oacc[mp][n] = __builtin_amdgcn_mfma_f32_16x16x32_bf16(vf[mp][kf], pb2[n][kf], oacc[mp][n], 0, 0, 0);
    }
    #pragma unroll
    for (int n = 0; n < 2; n++) {
        const float inv = 1.0f / lrow[n];
        const int q = q0 + n * 16 + cl;
        #pragma unroll
        for (int mp = 0; mp < 4; mp++) {
            uint2 pk2;
            pk2.x = cvtpk(oacc[mp][n][0] * inv, oacc[mp][n][1] * inv);
            pk2.y = cvtpk(oacc[mp][n][2] * inv, oacc[mp][n][3] * inv);
            *(uint2*)&y[(size_t)(b * 1024 + q) * 1024 + h * 64 + mp * 16 + rh * 4] = pk2;
        }
    }
}

// ---------------- host launcher ----------------
extern "C" void kernel_launch(void* const* d_in, const int* in_sizes, int n_in,
                              void* d_out, int out_size, void* d_ws, size_t ws_size,
                              hipStream_t stream) {
    const int*   idx   = (const int*)d_in[0];
    const float* tok   = (const float*)d_in[1];
    const float* pos   = (const float*)d_in[2];
    const float* ln1w  = (const float*)d_in[3];
    const float* ln1b  = (const float*)d_in[4];
    const float* Wq    = (const float*)d_in[5];
    const float* bq    = (const float*)d_in[6];
    const float* Wk    = (const float*)d_in[7];
    const float* bk    = (const float*)d_in[8];
    const float* Wv    = (const float*)d_in[9];
    const float* bv    = (const float*)d_in[10];
    const float* Wo    = (const float*)d_in[11];
    const float* bo    = (const float*)d_in[12];
    const float* ln2w  = (const float*)d_in[13];
    const float* ln2b  = (const float*)d_in[14];
    const float* W1    = (const float*)d_in[15];
    const float* b1    = (const float*)d_in[16];
    const float* W2    = (const float*)d_in[17];
    const float* b2    = (const float*)d_in[18];
    const float* lnfw  = (const float*)d_in[19];
    const float* lnfb  = (const float*)d_in[20];
    const float* headw = (const float*)d_in[21];

    char* ws = (char*)d_ws;
    size_t off = 0;
    auto nalloc = [&](size_t bytes) -> char* {
        char* p = ws + off;
        off = (off + bytes + 255) & ~(size_t)255;
        return p;
    };
    float* x     = (float*)nalloc((size_t)2048 * 1024 * 4);
    short* h     = (short*)nalloc((size_t)2048 * 1024 * 2);
    short* qkv   = (short*)nalloc((size_t)2048 * 3072 * 2);
    short* vtb   = (short*)nalloc((size_t)32 * 64 * 1024 * 2);
    short* y     = (short*)nalloc((size_t)2048 * 1024 * 2);
    short* u     = (short*)nalloc((size_t)2048 * 4096 * 2);
    float* mpart = (float*)nalloc((size_t)4 * 2048 * 1024 * 4);
    short* wqkv  = (short*)nalloc((size_t)4 * 3072 * 1024 * 2);
    short* wo    = (short*)nalloc((size_t)4 * 1024 * 1024 * 2);
    short* w1    = (short*)nalloc((size_t)4 * 4096 * 1024 * 2);
    short* w2    = (short*)nalloc((size_t)4 * 1024 * 4096 * 2);
    short* wh    = (short*)nalloc((size_t)32000 * 1024 * 2);
    float* bqkv  = (float*)nalloc((size_t)4 * 3072 * 4);

    // ---- weight prep ----
    k_bcat<<<48, 256, 0, stream>>>(bq, bk, bv, bqkv);
    k_tconv_all<<<20288, 256, 0, stream>>>(Wq, Wk, Wv, Wo, W1, W2, headw,
                                           wqkv, wo, w1, w2, wh);

    // ---- forward ----
    k_embedln<<<2048, 256, 0, stream>>>(idx, tok, pos, ln1w, ln1b, x, h);
    for (int lyr = 0; lyr < 4; lyr++) {
        k_gemm<2, 0><<<768, 256, 0, stream>>>(h, wqkv + (size_t)lyr * 3072 * 1024, bqkv + lyr * 3072,
                                              nullptr, qkv, 2048, 3072, 1024, 1024, 32, 1);
        k_vt<<<dim3(16, 32), 256, 0, stream>>>(qkv, vtb);
        k_attn<<<dim3(8, 32), 256, 0, stream>>>(qkv, vtb, y);
        k_gemm<2, 1><<<256, 256, 0, stream>>>(y, wo + (size_t)lyr * 1024 * 1024, bo + lyr * 1024,
                                              x, x, 2048, 1024, 1024, 1024, 32, 1);
        k_ln<<<2048, 256, 0, stream>>>(x, ln2w + lyr * 1024, ln2b + lyr * 1024, h);
        k_gemm<4, 2><<<512, 256, 0, stream>>>(h, w1 + (size_t)lyr * 4194304, b1 + lyr * 4096,
                                              nullptr, u, 2048, 4096, 1024, 1024, 16, 1);
        k_gemm<4, 3><<<512, 256, 0, stream>>>(u, w2 + (size_t)lyr * 4194304, nullptr,
                                              nullptr, mpart, 2048, 1024, 4096, 1024, 16, 4);
        const float* nw = (lyr < 3) ? (ln1w + (lyr + 1) * 1024) : lnfw;
        const float* nb = (lyr < 3) ? (ln1b + (lyr + 1) * 1024) : lnfb;
        k_redln<<<2048, 256, 0, stream>>>(mpart, b2 + lyr * 1024, x, nw, nb, h);
    }
    k_gemm8<<<1000, 512, 0, stream>>>(h, wh, (float*)d_out, 2048, 32000, 1024, 8);
    (void)in_sizes; (void)n_in; (void)out_size; (void)ws_size;
}

// Round 10
// 955.804 us; speedup vs baseline: 1.1382x; 1.0153x over previous
//
#include <hip/hip_runtime.h>
#include <hip/hip_bf16.h>

// GPT forward: B=2, T=1024, D=1024, H=16, HD=64, L=4, V=32000
// R10: (1) head k_gemm8: coalesced f32 epilogue via per-wave LDS staging
//      (dwordx4 1KB/instr stores; old path = 256B/instr scattered dwords).
//      (2) QKV GEMM EPI=4 writes V^T directly into vtb (k_vt deleted).

typedef __attribute__((ext_vector_type(8))) short s16x8;
typedef __attribute__((ext_vector_type(4))) float fx4;

__device__ __forceinline__ unsigned short f2bf(float f) {
    union { float f; unsigned int u; } v; v.f = f;
    unsigned int r = v.u + 0x7FFFu + ((v.u >> 16) & 1u);
    return (unsigned short)(r >> 16);
}

__device__ __forceinline__ void gload16(const short* g, short* l) {
    __builtin_amdgcn_global_load_lds((const __attribute__((address_space(1))) void*)g,
                                     (__attribute__((address_space(3))) void*)l, 16, 0, 0);
}

__device__ __forceinline__ unsigned cvtpk(float a, float b) {
    unsigned r;
    asm("v_cvt_pk_bf16_f32 %0, %1, %2" : "=v"(r) : "v"(a), "v"(b));
    return r;
}

// ---------------- embed + LN fused (row-local) ----------------
__global__ __launch_bounds__(256) void k_embedln(const int* __restrict__ idx,
                                                 const float* __restrict__ tok,
                                                 const float* __restrict__ pos,
                                                 const float* __restrict__ lw,
                                                 const float* __restrict__ lb,
                                                 float* __restrict__ x,
                                                 short* __restrict__ out) {
    int r = blockIdx.x;
    int t = r & 1023;
    int tokid = idx[r];
    int tid = threadIdx.x;
    float4 v = ((const float4*)(tok + (size_t)tokid * 1024))[tid];
    float4 vp = ((const float4*)(pos + (size_t)t * 1024))[tid];
    v.x += vp.x; v.y += vp.y; v.z += vp.z; v.w += vp.w;
    ((float4*)(x + (size_t)r * 1024))[tid] = v;
    float s = v.x + v.y + v.z + v.w;
    float ss = v.x*v.x + v.y*v.y + v.z*v.z + v.w*v.w;
    __shared__ float red[8];
    #pragma unroll
    for (int off = 32; off; off >>= 1) { s += __shfl_down(s, off); ss += __shfl_down(ss, off); }
    int wid = tid >> 6;
    if ((tid & 63) == 0) { red[wid] = s; red[4 + wid] = ss; }
    __syncthreads();
    s = red[0] + red[1] + red[2] + red[3];
    ss = red[4] + red[5] + red[6] + red[7];
    float mean = s * (1.0f / 1024.0f);
    float var = ss * (1.0f / 1024.0f) - mean * mean;
    float rstd = rsqrtf(var + 1e-5f);
    float4 wv = ((const float4*)lw)[tid];
    float4 bv = ((const float4*)lb)[tid];
    union { unsigned short us[4]; unsigned long long ll; } pk;
    pk.us[0] = f2bf((v.x - mean) * rstd * wv.x + bv.x);
    pk.us[1] = f2bf((v.y - mean) * rstd * wv.y + bv.y);
    pk.us[2] = f2bf((v.z - mean) * rstd * wv.z + bv.z);
    pk.us[3] = f2bf((v.w - mean) * rstd * wv.w + bv.w);
    ((unsigned long long*)(out + (size_t)r * 1024))[tid] = pk.ll;
}

// ---------------- layernorm (row of 1024), bf16 out ----------------
__global__ __launch_bounds__(256) void k_ln(const float* __restrict__ x,
                                            const float* __restrict__ w,
                                            const float* __restrict__ b,
                                            short* __restrict__ out) {
    int r = blockIdx.x;
    int tid = threadIdx.x;
    float4 v = ((const float4*)(x + (size_t)r * 1024))[tid];
    float s = v.x + v.y + v.z + v.w;
    float ss = v.x*v.x + v.y*v.y + v.z*v.z + v.w*v.w;
    __shared__ float red[8];
    #pragma unroll
    for (int off = 32; off; off >>= 1) { s += __shfl_down(s, off); ss += __shfl_down(ss, off); }
    int wid = tid >> 6;
    if ((tid & 63) == 0) { red[wid] = s; red[4 + wid] = ss; }
    __syncthreads();
    s = red[0] + red[1] + red[2] + red[3];
    ss = red[4] + red[5] + red[6] + red[7];
    float mean = s * (1.0f / 1024.0f);
    float var = ss * (1.0f / 1024.0f) - mean * mean;
    float rstd = rsqrtf(var + 1e-5f);
    float4 wv = ((const float4*)w)[tid];
    float4 bv = ((const float4*)b)[tid];
    union { unsigned short us[4]; unsigned long long ll; } pk;
    pk.us[0] = f2bf((v.x - mean) * rstd * wv.x + bv.x);
    pk.us[1] = f2bf((v.y - mean) * rstd * wv.y + bv.y);
    pk.us[2] = f2bf((v.z - mean) * rstd * wv.z + bv.z);
    pk.us[3] = f2bf((v.w - mean) * rstd * wv.w + bv.w);
    ((unsigned long long*)(out + (size_t)r * 1024))[tid] = pk.ll;
}

// ---------------- splitK reduce + bias + residual + LN fused ----------------
__global__ __launch_bounds__(256) void k_redln(const float* __restrict__ part,
                                               const float* __restrict__ bias,
                                               float* __restrict__ x,
                                               const float* __restrict__ lw,
                                               const float* __restrict__ lb,
                                               short* __restrict__ out) {
    const size_t PS = (size_t)2048 * 1024;
    const int r = blockIdx.x;
    const int tid = threadIdx.x;
    const size_t base = (size_t)r * 1024 + tid * 4;
    float4 a = *(const float4*)(part + base);
    float4 b = *(const float4*)(part + PS + base);
    float4 c = *(const float4*)(part + 2 * PS + base);
    float4 d = *(const float4*)(part + 3 * PS + base);
    float4 v = *(const float4*)(x + base);
    float4 bb = *(const float4*)(bias + tid * 4);
    v.x += a.x + b.x + c.x + d.x + bb.x;
    v.y += a.y + b.y + c.y + d.y + bb.y;
    v.z += a.z + b.z + c.z + d.z + bb.z;
    v.w += a.w + b.w + c.w + d.w + bb.w;
    *(float4*)(x + base) = v;
    float s = v.x + v.y + v.z + v.w;
    float ss = v.x*v.x + v.y*v.y + v.z*v.z + v.w*v.w;
    __shared__ float red[8];
    #pragma unroll
    for (int off = 32; off; off >>= 1) { s += __shfl_down(s, off); ss += __shfl_down(ss, off); }
    int wid = tid >> 6;
    if ((tid & 63) == 0) { red[wid] = s; red[4 + wid] = ss; }
    __syncthreads();
    s = red[0] + red[1] + red[2] + red[3];
    ss = red[4] + red[5] + red[6] + red[7];
    float mean = s * (1.0f / 1024.0f);
    float var = ss * (1.0f / 1024.0f) - mean * mean;
    float rstd = rsqrtf(var + 1e-5f);
    float4 wv = ((const float4*)lw)[tid];
    float4 bv = ((const float4*)lb)[tid];
    union { unsigned short us[4]; unsigned long long ll; } pk;
    pk.us[0] = f2bf((v.x - mean) * rstd * wv.x + bv.x);
    pk.us[1] = f2bf((v.y - mean) * rstd * wv.y + bv.y);
    pk.us[2] = f2bf((v.z - mean) * rstd * wv.z + bv.z);
    pk.us[3] = f2bf((v.w - mean) * rstd * wv.w + bv.w);
    ((unsigned long long*)(out + (size_t)r * 1024))[tid] = pk.ll;
}

// ---------------- batched transpose+convert: all weights, one dispatch ----------------
__global__ __launch_bounds__(256) void k_tconv_all(
        const float* __restrict__ Wq, const float* __restrict__ Wk,
        const float* __restrict__ Wv, const float* __restrict__ Wo,
        const float* __restrict__ W1, const float* __restrict__ W2,
        const float* __restrict__ Wh,
        short* __restrict__ wqkv, short* __restrict__ wo,
        short* __restrict__ w1, short* __restrict__ w2, short* __restrict__ wh) {
    const int bid = blockIdx.x;
    const float* src; short* dst; int K, N, tile;
    if (bid < 4096) {
        int seg = bid >> 10;
        int r = bid & 1023;
        int l = r >> 8; tile = r & 255;
        K = 1024; N = 1024;
        if (seg == 0)      { src = Wq + (size_t)l * 1048576; dst = wqkv + (size_t)l * 3145728; }
        else if (seg == 1) { src = Wk + (size_t)l * 1048576; dst = wqkv + (size_t)l * 3145728 + 1048576; }
        else if (seg == 2) { src = Wv + (size_t)l * 1048576; dst = wqkv + (size_t)l * 3145728 + 2097152; }
        else               { src = Wo + (size_t)l * 1048576; dst = wo + (size_t)l * 1048576; }
    } else if (bid < 8192) {
        int r = bid - 4096; int l = r >> 10; tile = r & 1023;
        K = 1024; N = 4096; src = W1 + (size_t)l * 4194304; dst = w1 + (size_t)l * 4194304;
    } else if (bid < 12288) {
        int r = bid - 8192; int l = r >> 10; tile = r & 1023;
        K = 4096; N = 1024; src = W2 + (size_t)l * 4194304; dst = w2 + (size_t)l * 4194304;
    } else {
        tile = bid - 12288; K = 1024; N = 32000; src = Wh; dst = wh;
    }
    const int nTiles = N >> 6;
    const int kt = tile / nTiles, ntl = tile - kt * nTiles;
    const int n0 = ntl * 64, k0 = kt * 64;

    __shared__ float tl[64][65];
    const int tid = threadIdx.x;
    const int c4 = tid & 15, rr = tid >> 4;
    #pragma unroll
    for (int j = 0; j < 4; j++) {
        int row = rr + j * 16;
        float4 vv = *(const float4*)(src + (size_t)(k0 + row) * N + n0 + c4 * 4);
        tl[row][c4*4+0] = vv.x; tl[row][c4*4+1] = vv.y;
        tl[row][c4*4+2] = vv.z; tl[row][c4*4+3] = vv.w;
    }
    __syncthreads();
    const int c8 = tid & 7, r2 = tid >> 3;
    #pragma unroll
    for (int j = 0; j < 2; j++) {
        int nrow = r2 + j * 32;
        union { unsigned short us[8]; s16x8 v; } pk;
        #pragma unroll
        for (int e = 0; e < 8; e++) pk.us[e] = f2bf(tl[c8*8+e][nrow]);
        *(s16x8*)&dst[(size_t)(n0 + nrow) * K + k0 + c8 * 8] = pk.v;
    }
}

// ---------------- concat qkv bias: [L][3072] ----------------
__global__ __launch_bounds__(256) void k_bcat(const float* __restrict__ bq,
                                              const float* __restrict__ bk,
                                              const float* __restrict__ bv,
                                              float* __restrict__ o) {
    int i = blockIdx.x * 256 + threadIdx.x;
    int l = i / 3072, c = i % 3072;
    float v = (c < 1024) ? bq[l*1024 + c] : ((c < 2048) ? bk[l*1024 + c - 1024] : bv[l*1024 + c - 2048]);
    o[i] = v;
}

// ---------------- 128-class GEMM (m97 structure), EPI + split-K support ----------------
// EPI: 0 = bias->bf16; 1 = f32 + residual; 2 = bias+GELU->bf16; 3 = f32 partial
// (no bias); 4 = QKV: bias->bf16 for Q/K cols, V cols transposed bf16 -> vtout
template<int MF, int EPI>
__global__ __launch_bounds__(256) void k_gemm(const short* __restrict__ A, const short* __restrict__ Bt,
                                              const float* bias, const float* res, void* Cout,
                                              short* vtout,
                                              int M, int N, int Kstride, int kLen,
                                              int mTiles, int nParts) {
    constexpr int BM = MF * 32;
    constexpr int IA = BM / 32;
    __shared__ __align__(16) short lA[BM * 64];
    __shared__ __align__(16) short lB[128 * 64];
    const int tid = threadIdx.x;
    const int l = tid & 63, w = tid >> 6;
    const int wr = w >> 1, wc = w & 1;
    const int per = gridDim.x >> 3;
    const int s2 = (blockIdx.x & 7) * per + (blockIdx.x >> 3);
    const int totPerN = mTiles * nParts;
    const int nt = s2 / totPerN;
    const int rem = s2 - nt * totPerN;
    const int part = rem / mTiles, mt = rem - part * mTiles;
    const int k0 = part * kLen;
    const int m0 = mt * BM, n0 = nt * 128;
    const int cl = l & 15, rh = l >> 4;
    fx4 acc[MF][4] = {};

    const int lr = l >> 3, c8 = l & 7;
    const short* pa[IA];
    const short* pb[4];
    #pragma unroll
    for (int j = 0; j < IA; j++) {
        const int row = w * (BM / 4) + j * 8 + lr;
        pa[j] = A + (size_t)(m0 + row) * Kstride + k0 + ((c8 ^ (row & 7)) << 3);
    }
    #pragma unroll
    for (int j = 0; j < 4; j++) {
        const int row = w * 32 + j * 8 + lr;
        pb[j] = Bt + (size_t)(n0 + row) * Kstride + k0 + ((c8 ^ (row & 7)) << 3);
    }

    for (int kt = 0; kt < kLen; kt += 64) {
        #pragma unroll
        for (int j = 0; j < IA; j++)
            gload16(pa[j] + kt, &lA[(w * (BM / 4) + j * 8) * 64]);
        #pragma unroll
        for (int j = 0; j < 4; j++)
            gload16(pb[j] + kt, &lB[(w * 32 + j * 8) * 64]);
        __syncthreads();
        #pragma unroll
        for (int kk = 0; kk < 2; kk++) {
            s16x8 af[MF], bfr[4];
            const int kc = kk * 4 + rh;
            const int ko = (kc ^ (cl & 7)) * 8;
            #pragma unroll
            for (int mf = 0; mf < MF; mf++)
                af[mf] = *(const s16x8*)&lA[(wr * (MF * 16) + mf * 16 + cl) * 64 + ko];
            #pragma unroll
            for (int nf = 0; nf < 4; nf++)
                bfr[nf] = *(const s16x8*)&lB[(wc * 64 + nf * 16 + cl) * 64 + ko];
            #pragma unroll
            for (int mf = 0; mf < MF; mf++)
                #pragma unroll
                for (int nf = 0; nf < 4; nf++)
                    acc[mf][nf] = __builtin_amdgcn_mfma_f32_16x16x32_bf16(af[mf], bfr[nf], acc[mf][nf], 0, 0, 0);
        }
        __syncthreads();
    }
    float* Cp = (float*)Cout + (size_t)part * M * N;
    #pragma unroll
    for (int nf = 0; nf < 4; nf++) {
        const int col = n0 + wc * 64 + nf * 16 + cl;
        const float bv = (EPI == 3) ? 0.0f : bias[col];
        #pragma unroll
        for (int mf = 0; mf < MF; mf++) {
            const int rbase = m0 + wr * (MF * 16) + mf * 16 + rh * 4;
            if constexpr (EPI == 4) {
                float vv[4];
                #pragma unroll
                for (int r = 0; r < 4; r++) vv[r] = acc[mf][nf][r] + bv;
                if (n0 >= 2048) {
                    // V block: write transposed bf16 into vtout
                    const int cc = col - 2048;
                    const int bidx = rbase >> 10, t0v = rbase & 1023;
                    uint2 pk2;
                    pk2.x = cvtpk(vv[0], vv[1]);
                    pk2.y = cvtpk(vv[2], vv[3]);
                    *(uint2*)&vtout[(size_t)((bidx * 16 + (cc >> 6)) * 64 + (cc & 63)) * 1024 + t0v] = pk2;
                } else {
                    #pragma unroll
                    for (int r = 0; r < 4; r++)
                        ((unsigned short*)Cout)[(size_t)(rbase + r) * N + col] = f2bf(vv[r]);
                }
            } else {
                #pragma unroll
                for (int r = 0; r < 4; r++) {
                    float v = acc[mf][nf][r] + bv;
                    const size_t off = (size_t)(rbase + r) * N + col;
                    if constexpr (EPI == 0) {
                        ((unsigned short*)Cout)[off] = f2bf(v);
                    } else if constexpr (EPI == 1) {
                        ((float*)Cout)[off] = v + res[off];
                    } else if constexpr (EPI == 2) {
                        v = 0.5f * v * (1.0f + erff(v * 0.70710678118654752f));
                        ((unsigned short*)Cout)[off] = f2bf(v);
                    } else {
                        Cp[off] = v;
                    }
                }
            }
        }
    }
}

// ---------------- 8-phase 256x256 GEMM (head), f32 out, no bias ----------------
#define PH_CORE(MB) \
    __builtin_amdgcn_s_barrier(); \
    __builtin_amdgcn_s_setprio(1); \
    _Pragma("unroll") \
    for (int nf_ = 0; nf_ < 4; ++nf_) { \
        acc[MB][nf_]   = __builtin_amdgcn_mfma_f32_16x16x32_bf16(af[0][0], bf[nf_][0], acc[MB][nf_], 0, 0, 0); \
        acc[MB][nf_]   = __builtin_amdgcn_mfma_f32_16x16x32_bf16(af[0][1], bf[nf_][1], acc[MB][nf_], 0, 0, 0); \
        acc[MB+1][nf_] = __builtin_amdgcn_mfma_f32_16x16x32_bf16(af[1][0], bf[nf_][0], acc[MB+1][nf_], 0, 0, 0); \
        acc[MB+1][nf_] = __builtin_amdgcn_mfma_f32_16x16x32_bf16(af[1][1], bf[nf_][1], acc[MB+1][nf_], 0, 0, 0); \
    } \
    __builtin_amdgcn_s_setprio(0);

#define PHN(MB) \
    PH_CORE(MB) \
    asm volatile("" ::: "memory"); \
    __builtin_amdgcn_s_barrier(); \
    asm volatile("" ::: "memory");

#define PHW(MB) \
    PH_CORE(MB) \
    asm volatile("s_waitcnt vmcnt(4)" ::: "memory"); \
    __builtin_amdgcn_s_barrier(); \
    asm volatile("" ::: "memory");

__global__ __launch_bounds__(512, 1)
void k_gemm8(const short* __restrict__ A, const short* __restrict__ Bt,
             float* __restrict__ C, int M, int N, int K, int mTiles) {
    __shared__ __align__(16) short lA[2][256 * 64];
    __shared__ __align__(16) short lB[2][256 * 64];
    const int tid = threadIdx.x;
    const int l = tid & 63, w = tid >> 6;
    const int wr = w >> 2, wc = w & 3;
    const int per = gridDim.x >> 3;
    const int s2 = (blockIdx.x & 7) * per + (blockIdx.x >> 3);
    const int nt0 = s2 / mTiles, mt = s2 - nt0 * mTiles;
    const int m0 = mt * 256, n0 = nt0 * 256;
    const int cl = l & 15, rh = l >> 4;

    fx4 acc[8][4] = {};

    const int srow = tid >> 3, sc8 = tid & 7;
    const short* pA[2][2]; const short* pB[2][2];
    #pragma unroll
    for (int hh = 0; hh < 2; ++hh)
        #pragma unroll
        for (int j = 0; j < 2; ++j) {
            const int row = hh * 128 + j * 64 + srow;
            const int cg = (sc8 ^ (row & 7)) << 3;
            pA[hh][j] = A + (size_t)(m0 + row) * K + cg;
            pB[hh][j] = Bt + (size_t)(n0 + row) * K + cg;
        }

    auto stageA = [&](int b, int hh, int kt) {
        #pragma unroll
        for (int j = 0; j < 2; ++j)
            gload16(pA[hh][j] + (kt << 6), &lA[b][(hh * 128 + j * 64 + w * 8) * 64]);
    };
    auto stageB = [&](int b, int hh, int kt) {
        #pragma unroll
        for (int j = 0; j < 2; ++j)
            gload16(pB[hh][j] + (kt << 6), &lB[b][(hh * 128 + j * 64 + w * 8) * 64]);
    };
    auto readA = [&](int b, int mf, int kk) -> s16x8 {
        const int row = wr * 128 + mf * 16 + cl;
        return *(const s16x8*)&lA[b][(row << 6) + (((kk * 4 + rh) ^ (row & 7)) << 3)];
    };
    auto readB = [&](int b, int nf, int kk) -> s16x8 {
        const int row = wc * 64 + nf * 16 + cl;
        return *(const s16x8*)&lB[b][(row << 6) + (((kk * 4 + rh) ^ (row & 7)) << 3)];
    };

    const int NT = K >> 6;
    stageA(0, 0, 0); stageA(0, 1, 0);
    stageB(0, 0, 0); stageB(0, 1, 0);
    stageB(1, 0, 1); stageB(1, 1, 1);
    asm volatile("s_waitcnt vmcnt(4)" ::: "memory");
    __builtin_amdgcn_s_barrier();
    asm volatile("" ::: "memory");

    s16x8 bf[4][2], af[2][2];
    for (int c = 0; c < (NT >> 1); ++c) {
        const int kt = c << 1;
        const int k1 = kt + 1;
        const int k2 = (kt + 2 < NT) ? kt + 2 : NT - 1;
        const int k3 = (kt + 3 < NT) ? kt + 3 : NT - 1;

        #pragma unroll
        for (int nf = 0; nf < 4; ++nf) { bf[nf][0] = readB(0, nf, 0); bf[nf][1] = readB(0, nf, 1); }
        af[0][0] = readA(0, 0, 0); af[0][1] = readA(0, 0, 1);
        af[1][0] = readA(0, 1, 0); af[1][1] = readA(0, 1, 1);
        stageA(1, 0, k1); stageA(1, 1, k1);
        PHN(0)
        af[0][0] = readA(0, 2, 0); af[0][1] = readA(0, 2, 1);
        af[1][0] = readA(0, 3, 0); af[1][1] = readA(0, 3, 1);
        stageB(0, 0, k2);
        PHN(2)
        af[0][0] = readA(0, 4, 0); af[0][1] = readA(0, 4, 1);
        af[1][0] = readA(0, 5, 0); af[1][1] = readA(0, 5, 1);
        stageB(0, 1, k2);
        PHN(4)
        af[0][0] = readA(0, 6, 0); af[0][1] = readA(0, 6, 1);
        af[1][0] = readA(0, 7, 0); af[1][1] = readA(0, 7, 1);
        PHW(6)
        #pragma unroll
        for (int nf = 0; nf < 4; ++nf) { bf[nf][0] = readB(1, nf, 0); bf[nf][1] = readB(1, nf, 1); }
        af[0][0] = readA(1, 0, 0); af[0][1] = readA(1, 0, 1);
        af[1][0] = readA(1, 1, 0); af[1][1] = readA(1, 1, 1);
        stageA(0, 0, k2);
        PHN(0)
        af[0][0] = readA(1, 2, 0); af[0][1] = readA(1, 2, 1);
        af[1][0] = readA(1, 3, 0); af[1][1] = readA(1, 3, 1);
        stageA(0, 1, k2);
        PHN(2)
        af[0][0] = readA(1, 4, 0); af[0][1] = readA(1, 4, 1);
        af[1][0] = readA(1, 5, 0); af[1][1] = readA(1, 5, 1);
        stageB(1, 0, k3);
        PHN(4)
        af[0][0] = readA(1, 6, 0); af[0][1] = readA(1, 6, 1);
        af[1][0] = readA(1, 7, 0); af[1][1] = readA(1, 7, 1);
        stageB(1, 1, k3);
        PHW(6)
    }

    // ---- coalesced epilogue: stage per-wave acc rows in LDS, dwordx4 stores ----
    // per-wave region: 16 rows x 68 f32 (pad) = 4352 B, wave-local (no barriers;
    // final loop barrier already ordered all lA reads before these writes)
    float* eld = (float*)((char*)&lA[0][0] + w * 4352);
    const int erow = l >> 4, ec4 = (l & 15) * 4;
    #pragma unroll
    for (int mf = 0; mf < 8; ++mf) {
        #pragma unroll
        for (int nf = 0; nf < 4; ++nf)
            #pragma unroll
            for (int r = 0; r < 4; ++r)
                eld[(rh * 4 + r) * 68 + nf * 16 + cl] = acc[mf][nf][r];
        asm volatile("s_waitcnt lgkmcnt(0)" ::: "memory");
        #pragma unroll
        for (int s = 0; s < 4; ++s) {
            const int rr2 = s * 4 + erow;
            float4 vv = *(const float4*)&eld[rr2 * 68 + ec4];
            *(float4*)&C[(size_t)(m0 + wr * 128 + mf * 16 + rr2) * N + n0 + wc * 64 + ec4] = vv;
        }
        asm volatile("s_waitcnt lgkmcnt(0)" ::: "memory");
    }
}

// ---------------- fused causal attention: swapped QK^T, global K/V (R6/R9) ----------------
__global__ __launch_bounds__(256) void k_attn(const short* __restrict__ qkv,
                                              const short* __restrict__ vt,
                                              short* __restrict__ y) {
    const int bh = blockIdx.y, qt = blockIdx.x;
    const int b = bh >> 4, h = bh & 15;
    const int w = threadIdx.x >> 6, l = threadIdx.x & 63;
    const int cl = l & 15, rh = l >> 4;
    const int q0 = qt * 128 + w * 32;
    const short* qbase = qkv + (size_t)b * 1024 * 3072 + h * 64;
    const short* kbase = qbase + 1024;
    const short* vbase = vt + (size_t)bh * 64 * 1024;
    __shared__ __align__(16) short plds[4][32][64];
    char* pbase = (char*)&plds[w][0][0];

    s16x8 qf[2][2];
    #pragma unroll
    for (int n = 0; n < 2; n++)
        #pragma unroll
        for (int kf = 0; kf < 2; kf++)
            qf[n][kf] = *(const s16x8*)&qbase[(size_t)(q0 + n * 16 + cl) * 3072 + kf * 32 + rh * 8];

    fx4 oacc[4][2] = {};
    float mrow[2] = {-3e38f, -3e38f}, lrow[2] = {0.0f, 0.0f};
    const float SC = 0.125f * 1.44269504088896f;

    const int ntile = (q0 + 95) >> 6;
    for (int it = 0; it < ntile; it++) {
        const int t0 = it * 64;
        fx4 s[4][2] = {};
        #pragma unroll
        for (int kf = 0; kf < 2; kf++) {
            s16x8 kfr[4];
            #pragma unroll
            for (int m = 0; m < 4; m++)
                kfr[m] = *(const s16x8*)&kbase[(size_t)(t0 + m * 16 + cl) * 3072 + kf * 32 + rh * 8];
            #pragma unroll
            for (int m = 0; m < 4; m++)
                #pragma unroll
                for (int n = 0; n < 2; n++)
                    s[m][n] = __builtin_amdgcn_mfma_f32_16x16x32_bf16(kfr[m], qf[n][kf], s[m][n], 0, 0, 0);
        }
        const bool domask = (t0 + 63) > q0;
        #pragma unroll
        for (int n = 0; n < 2; n++) {
            const int q = q0 + n * 16 + cl;
            float tmax = -3e38f;
            #pragma unroll
            for (int m = 0; m < 4; m++)
                #pragma unroll
                for (int r = 0; r < 4; r++) {
                    float v = s[m][n][r] * SC;
                    if (domask && (t0 + m * 16 + rh * 4 + r) > q) v = -3e38f;
                    s[m][n][r] = v;
                    tmax = fmaxf(tmax, v);
                }
            tmax = fmaxf(tmax, __shfl_xor(tmax, 16));
            tmax = fmaxf(tmax, __shfl_xor(tmax, 32));
            const float mnew = fmaxf(mrow[n], tmax);
            const float alpha = exp2f(mrow[n] - mnew);
            mrow[n] = mnew;
            float rsum = 0.0f;
            #pragma unroll
            for (int m = 0; m < 4; m++)
                #pragma unroll
                for (int r = 0; r < 4; r++) {
                    float p = exp2f(s[m][n][r] - mnew);
                    s[m][n][r] = p;
                    rsum += p;
                }
            rsum += __shfl_xor(rsum, 16);
            rsum += __shfl_xor(rsum, 32);
            lrow[n] = lrow[n] * alpha + rsum;
            #pragma unroll
            for (int mp = 0; mp < 4; mp++)
                #pragma unroll
                for (int r = 0; r < 4; r++)
                    oacc[mp][n][r] *= alpha;
        }
        #pragma unroll
        for (int n = 0; n < 2; n++) {
            const int qr = n * 16 + cl;
            const int sw = (qr & 7) << 4;
            #pragma unroll
            for (int m = 0; m < 4; m++) {
                uint2 pk2;
                pk2.x = cvtpk(s[m][n][0], s[m][n][1]);
                pk2.y = cvtpk(s[m][n][2], s[m][n][3]);
                const int off = qr * 128 + ((m * 32 + rh * 8) ^ sw);
                *(uint2*)(pbase + off) = pk2;
            }
        }
        s16x8 pb2[2][2];
        #pragma unroll
        for (int n = 0; n < 2; n++) {
            const int qr = n * 16 + cl;
            const int sw = (qr & 7) << 4;
            #pragma unroll
            for (int kf = 0; kf < 2; kf++)
                pb2[n][kf] = *(const s16x8*)(pbase + qr * 128 + ((kf * 64 + rh * 16) ^ sw));
        }
        s16x8 vf[4][2];
        #pragma unroll
        for (int mp = 0; mp < 4; mp++)
            #pragma unroll
            for (int kf = 0; kf < 2; kf++)
                vf[mp][kf] = *(const s16x8*)&vbase[(size_t)(mp * 16 + cl) * 1024 + t0 + kf * 32 + rh * 8];
        #pragma unroll
        for (int mp = 0; mp < 4; mp++)
            #pragma unroll
            for (int n = 0; n < 2; n++)
                #pragma unroll
                for (int kf = 0; kf < 2; kf++)
                    oacc[mp][n] = __builtin_amdgcn_mfma_f32_16x16x32_bf16(vf[mp][kf], pb2[n][kf], oacc[mp][n], 0, 0, 0);
    }
    #pragma unroll
    for (int n = 0; n < 2; n++) {
        const float inv = 1.0f / lrow[n];
        const int q = q0 + n * 16 + cl;
        #pragma unroll
        for (int mp = 0; mp < 4; mp++) {
            uint2 pk2;
            pk2.x = cvtpk(oacc[mp][n][0] * inv, oacc[mp][n][1] * inv);
            pk2.y = cvtpk(oacc[mp][n][2] * inv, oacc[mp][n][3] * inv);
            *(uint2*)&y[(size_t)(b * 1024 + q) * 1024 + h * 64 + mp * 16 + rh * 4] = pk2;
        }
    }
}

// ---------------- host launcher ----------------
extern "C" void kernel_launch(void* const* d_in, const int* in_sizes, int n_in,
                              void* d_out, int out_size, void* d_ws, size_t ws_size,
                              hipStream_t stream) {
    const int*   idx   = (const int*)d_in[0];
    const float* tok   = (const float*)d_in[1];
    const float* pos   = (const float*)d_in[2];
    const float* ln1w  = (const float*)d_in[3];
    const float* ln1b  = (const float*)d_in[4];
    const float* Wq    = (const float*)d_in[5];
    const float* bq    = (const float*)d_in[6];
    const float* Wk    = (const float*)d_in[7];
    const float* bk    = (const float*)d_in[8];
    const float* Wv    = (const float*)d_in[9];
    const float* bv    = (const float*)d_in[10];
    const float* Wo    = (const float*)d_in[11];
    const float* bo    = (const float*)d_in[12];
    const float* ln2w  = (const float*)d_in[13];
    const float* ln2b  = (const float*)d_in[14];
    const float* W1    = (const float*)d_in[15];
    const float* b1    = (const float*)d_in[16];
    const float* W2    = (const float*)d_in[17];
    const float* b2    = (const float*)d_in[18];
    const float* lnfw  = (const float*)d_in[19];
    const float* lnfb  = (const float*)d_in[20];
    const float* headw = (const float*)d_in[21];

    char* ws = (char*)d_ws;
    size_t off = 0;
    auto nalloc = [&](size_t bytes) -> char* {
        char* p = ws + off;
        off = (off + bytes + 255) & ~(size_t)255;
        return p;
    };
    float* x     = (float*)nalloc((size_t)2048 * 1024 * 4);
    short* h     = (short*)nalloc((size_t)2048 * 1024 * 2);
    short* qkv   = (short*)nalloc((size_t)2048 * 3072 * 2);
    short* vtb   = (short*)nalloc((size_t)32 * 64 * 1024 * 2);
    short* y     = (short*)nalloc((size_t)2048 * 1024 * 2);
    short* u     = (short*)nalloc((size_t)2048 * 4096 * 2);
    float* mpart = (float*)nalloc((size_t)4 * 2048 * 1024 * 4);
    short* wqkv  = (short*)nalloc((size_t)4 * 3072 * 1024 * 2);
    short* wo    = (short*)nalloc((size_t)4 * 1024 * 1024 * 2);
    short* w1    = (short*)nalloc((size_t)4 * 4096 * 1024 * 2);
    short* w2    = (short*)nalloc((size_t)4 * 1024 * 4096 * 2);
    short* wh    = (short*)nalloc((size_t)32000 * 1024 * 2);
    float* bqkv  = (float*)nalloc((size_t)4 * 3072 * 4);

    // ---- weight prep ----
    k_bcat<<<48, 256, 0, stream>>>(bq, bk, bv, bqkv);
    k_tconv_all<<<20288, 256, 0, stream>>>(Wq, Wk, Wv, Wo, W1, W2, headw,
                                           wqkv, wo, w1, w2, wh);

    // ---- forward ----
    k_embedln<<<2048, 256, 0, stream>>>(idx, tok, pos, ln1w, ln1b, x, h);
    for (int lyr = 0; lyr < 4; lyr++) {
        k_gemm<2, 4><<<768, 256, 0, stream>>>(h, wqkv + (size_t)lyr * 3072 * 1024, bqkv + lyr * 3072,
                                              nullptr, qkv, vtb, 2048, 3072, 1024, 1024, 32, 1);
        k_attn<<<dim3(8, 32), 256, 0, stream>>>(qkv, vtb, y);
        k_gemm<2, 1><<<256, 256, 0, stream>>>(y, wo + (size_t)lyr * 1024 * 1024, bo + lyr * 1024,
                                              x, x, nullptr, 2048, 1024, 1024, 1024, 32, 1);
        k_ln<<<2048, 256, 0, stream>>>(x, ln2w + lyr * 1024, ln2b + lyr * 1024, h);
        k_gemm<4, 2><<<512, 256, 0, stream>>>(h, w1 + (size_t)lyr * 4194304, b1 + lyr * 4096,
                                              nullptr, u, nullptr, 2048, 4096, 1024, 1024, 16, 1);
        k_gemm<4, 3><<<512, 256, 0, stream>>>(u, w2 + (size_t)lyr * 4194304, nullptr,
                                              nullptr, mpart, nullptr, 2048, 1024, 4096, 1024, 16, 4);
        const float* nw = (lyr < 3) ? (ln1w + (lyr + 1) * 1024) : lnfw;
        const float* nb = (lyr < 3) ? (ln1b + (lyr + 1) * 1024) : lnfb;
        k_redln<<<2048, 256, 0, stream>>>(mpart, b2 + lyr * 1024, x, nw, nb, h);
    }
    k_gemm8<<<1000, 512, 0, stream>>>(h, wh, (float*)d_out, 2048, 32000, 1024, 8);
    (void)in_sizes; (void)n_in; (void)out_size; (void)ws_size;
}